// Round 10
// baseline (6167.746 us; speedup 1.0000x reference)
//
#include <hip/hip_runtime.h>

typedef __attribute__((ext_vector_type(8))) short s8v;   // 8 x bf16 (4 VGPRs)
typedef __attribute__((ext_vector_type(4))) float f4v;   // MFMA accumulator

#define BB 8
#define TT 500
#define UU 120
#define UP1 121
#define VV 128
#define HH 320
#define G4 1280

// ---------------- helpers ----------------
__device__ __forceinline__ unsigned short f2bf(float x) {
  unsigned u = __builtin_bit_cast(unsigned, x);
  unsigned r = (u + 0x7FFFu + ((u >> 16) & 1u)) >> 16;  // RNE
  return (unsigned short)r;
}
__device__ __forceinline__ float sigf(float x)   { return 1.f / (1.f + __expf(-x)); }
__device__ __forceinline__ float tanh_f(float x) { return 2.f / (1.f + __expf(-2.f * x)) - 1.f; }

// agent-scope (L3-coherent) relaxed atomics — proven transport
__device__ __forceinline__ unsigned ald32(const unsigned* p) {
  return __hip_atomic_load((unsigned*)p, __ATOMIC_RELAXED, __HIP_MEMORY_SCOPE_AGENT);
}
__device__ __forceinline__ void ast32(unsigned* p, unsigned v) {
  __hip_atomic_store(p, v, __ATOMIC_RELAXED, __HIP_MEMORY_SCOPE_AGENT);
}

// ---------------- prep: out init ----------------
__global__ void prep_zero(float* out) {
  if (threadIdx.x == 0 && blockIdx.x == 0) out[0] = 0.f;
}

// ---------------- prep: bf16 conversions + bias folds ----------------
__global__ void prep_w(
    const float* __restrict__ whh0, const float* __restrict__ wih1,
    const float* __restrict__ whh1, const float* __restrict__ whhd,
    const float* __restrict__ wih0, const float* __restrict__ xs,
    const float* __restrict__ ewo,  const float* __restrict__ dwo,
    const float* __restrict__ bih1, const float* __restrict__ bhh1,
    const float* __restrict__ bih0, const float* __restrict__ bhh0,
    ushort* __restrict__ wb, ushort* __restrict__ wih0b, ushort* __restrict__ xsb,
    ushort* __restrict__ wob, ushort* __restrict__ dwob,
    float* __restrict__ bias1p, float* __restrict__ b0s)
{
  int i = blockIdx.x * blockDim.x + threadIdx.x;
  if (i < 1638400) {                       // 4 recurrent-ish mats [1280][320]
    int m = i / 409600, e = i - m * 409600;
    const float* src = (m == 0) ? whh0 : (m == 1) ? wih1 : (m == 2) ? whh1 : whhd;
    wb[i] = f2bf(src[e]);
  } else if (i < 1761280) {                // Wih0 [1280][80] -> [1280][96] zero-padded
    int e = i - 1638400;
    int row = e / 96, k = e - row * 96;
    wih0b[e] = (k < 80) ? f2bf(wih0[row * 80 + k]) : (ushort)0;
  } else if (i < 2145280) {                // xs [4000][80] -> [4000][96] zero-padded
    int e = i - 1761280;
    int row = e / 96, k = e - row * 96;
    xsb[e] = (k < 80) ? f2bf(xs[row * 80 + k]) : (ushort)0;
  } else if (i < 2186240) {                // enc_Wo [128][320]
    int e = i - 2145280;
    wob[e] = f2bf(ewo[e]);
  } else if (i < 2227200) {                // dec_Wo [128][320]
    int e = i - 2186240;
    dwob[e] = f2bf(dwo[e]);
  } else if (i < 2228480) {                // bias1 permuted [unit][gate]
    int e = i - 2227200;
    int uq = e >> 2, gq = e & 3;
    bias1p[e] = bih1[gq * HH + uq] + bhh1[gq * HH + uq];
  } else if (i < 2229760) {                // bih0+bhh0 summed (gate-row order)
    int e = i - 2228480;
    b0s[e] = bih0[e] + bhh0[e];
  }
}

// ---------------- xproj for layer0: [4000,96]bf16 @ [96,1280] -> xp0[b][t][u][g] f32 ----------------
__global__ __launch_bounds__(256) void xproj0_mfma(
    const ushort* __restrict__ xsb, const ushort* __restrict__ wih0b,
    const float* __restrict__ b0s, float* __restrict__ xp0)
{
  const int mt = blockIdx.x;                 // 250 tiles of 16 (b,t)-rows
  const int wave = threadIdx.x >> 6, lane = threadIdx.x & 63;
  const int q = lane >> 4, n16 = lane & 15;
  s8v a[3];
#pragma unroll
  for (int kt = 0; kt < 3; kt++)
    a[kt] = *(const s8v*)(xsb + (mt * 16 + n16) * 96 + kt * 32 + q * 8);
  for (int nt = wave; nt < 80; nt += 4) {
    s8v bf[3];
#pragma unroll
    for (int kt = 0; kt < 3; kt++)
      bf[kt] = *(const s8v*)(wih0b + (nt * 16 + n16) * 96 + kt * 32 + q * 8);
    f4v acc = {0.f, 0.f, 0.f, 0.f};
#pragma unroll
    for (int kt = 0; kt < 3; kt++)
      acc = __builtin_amdgcn_mfma_f32_16x16x32_bf16(a[kt], bf[kt], acc, 0, 0, 0);
    const int gr = nt * 16 + n16;            // D col = gate row
    const int gg = gr / HH;
    const int uu = gr - gg * HH;
    const float bias = b0s[gr];
#pragma unroll
    for (int r = 0; r < 4; r++) {
      int bt = mt * 16 + 4 * q + r;          // D row = (b,t) row
      xp0[(size_t)bt * G4 + uu * 4 + gg] = acc[r] + bias;
    }
  }
}

// ---------------- decoder input projection: one-hot gather ----------------
__global__ __launch_bounds__(256) void xprojd_g(
    const int* __restrict__ ys, const float* __restrict__ dWih,
    const float* __restrict__ dbih, const float* __restrict__ dbhh,
    float* __restrict__ xpd)
{
  const int blk = blockIdx.x;                // 968 = 8 * 121
  const int b = blk / UP1, u = blk - b * UP1;
  int colv = -1;
  if (u > 0) colv = ys[b * UU + (u - 1)] - 1;   // embed row id>=1 -> one-hot at id-1
  for (int i = threadIdx.x; i < G4; i += 256) {
    int uu = i >> 2, gg = i & 3;
    int row = gg * HH + uu;
    float v = dbih[row] + dbhh[row];
    if (colv >= 0) v += dWih[row * 127 + colv];
    xpd[((size_t)b * UP1 + u) * G4 + i] = v;
  }
}

// ======================================================================
// Fused pipeline v8: everything after the prep chain lives in ONE kernel.
// 26 WGs x 512 thr:
//   wg 0-4  : stage0, wg 5-9: stage1, wg 10-14: dec  (UNCHANGED from R8)
//   wg 15-19: relay xp1 = Wih1@h0[s+1] + b1           (UNCHANGED from R8)
//   wg 20-23: enc-proj + FUSED LSE, t stride 4: poll h1[t+1], MFMA with
//             LDS-staged Wo, keep enc[t] in LDS (never written to global),
//             then compute lb/ly[t] (tagged f32) with depth-4 pipelined
//             agent-scope dec2 reads. Gated once on dec2-done flag.
//   wg 24   : dec-proj: poll hd[t+1], write dec2 (agent-scope stores),
//             then vmcnt(0) + barrier + tagged done-flag (R6-proven drain).
//   wg 25   : dp (RNN-T forward), 8 waves = 8 samples, barrier-free shuffle
//             form, TAGGED lb/ly reads -> trails the lse stream; atomicAdd
//             of the final nll into out.
// All cross-WG edges one-way or self-cycles; every spin is bounded.
// ======================================================================

#define LSE_ISSUE(R, I) { int p_ = (I)*16 + wave*2 + half;                      \
  if (p_ < 968) { int u_ = p_ >> 3, b_ = p_ & 7;                                \
    const unsigned* dr_ = d2u + (size_t)(u_*16 + b_) * VV + ll;                 \
    R[0]=ald32(dr_); R[1]=ald32(dr_+32); R[2]=ald32(dr_+64); R[3]=ald32(dr_+96);} }

#define LSE_PROC(R, I) { int p_ = (I)*16 + wave*2 + half;                       \
  if (p_ < 968) { int u_ = p_ >> 3, b_ = p_ & 7;                                \
    float s0_ = encL[b_][ll]      + __uint_as_float(R[0]);                      \
    float s1_ = encL[b_][ll+32]   + __uint_as_float(R[1]);                      \
    float s2_ = encL[b_][ll+64]   + __uint_as_float(R[2]);                      \
    float s3_ = encL[b_][ll+96]   + __uint_as_float(R[3]);                      \
    float mx_ = fmaxf(fmaxf(s0_,s1_), fmaxf(s2_,s3_));                          \
    _Pragma("unroll") for (int o_=1;o_<=16;o_<<=1) mx_ = fmaxf(mx_, __shfl_xor(mx_,o_)); \
    int y_ = (u_ < UU) ? ys[b_*UU+u_] : -1;                                     \
    float ps_ = __expf(s0_-mx_)+__expf(s1_-mx_)+__expf(s2_-mx_)+__expf(s3_-mx_);\
    float sy_ = (ll==y_)?s0_:((ll+32==y_)?s1_:((ll+64==y_)?s2_:((ll+96==y_)?s3_:0.f))); \
    _Pragma("unroll") for (int o_=1;o_<=16;o_<<=1) { ps_ += __shfl_xor(ps_,o_); sy_ += __shfl_xor(sy_,o_);} \
    float lse_ = mx_ + __logf(ps_);                                             \
    if (ll == 0) {                                                              \
      ast32((unsigned*)(lbp + ((size_t)b_*TT + t)*UP1 + u_), __float_as_uint(s0_-lse_)|1u); \
      if (u_ < UU) ast32((unsigned*)(lyp + ((size_t)b_*TT + t)*UU + u_), __float_as_uint(sy_-lse_)|1u); } } }

__global__ __launch_bounds__(512, 1) void lstm_fused(
    const ushort* __restrict__ wb, const float* __restrict__ b1p,
    const float* __restrict__ xp0, const float* __restrict__ xpd,
    unsigned* __restrict__ h0u, unsigned* __restrict__ h1u, unsigned* __restrict__ hdu,
    unsigned* __restrict__ xp1u,
    const ushort* __restrict__ wob, const ushort* __restrict__ dwob,
    const float* __restrict__ ebo, const float* __restrict__ dbo,
    float* __restrict__ dec2, float* __restrict__ lbp, float* __restrict__ lyp,
    const int* __restrict__ ys, const int* __restrict__ xlen,
    const int* __restrict__ ylen, float* __restrict__ out,
    unsigned* __restrict__ dflag)
{
  __shared__ ushort hbS[2][16][328];         // 21KB  h double-buffer [b][u]
  __shared__ s8v wlds[8][10][64];            // 80KB  tile1 weight frags / proj Wo
  __shared__ float encL[8][VV];              // 4KB   enc row for fused lse

  const int wg = blockIdx.x;
  const int tid = threadIdx.x;
  const int wave = tid >> 6, lane = tid & 63;
  const int q = lane >> 4, n16 = lane & 15;
  const int uloc = n16 >> 2, g = n16 & 3;
  const int bcol = n16 & 7;
  const bool act = (n16 < BB);

  // zero both LDS h buffers (t=0 state = zeros; rows 8..15 stay zero forever)
  for (int i = tid; i < 2 * 16 * 328; i += 512) ((ushort*)hbS)[i] = 0;

  if (wg == 25) {
    // ================= dp: RNN-T forward DP, wave = sample =================
    const int b = wave;
    const int l = lane;
    const int u0 = 2 * l, u1 = 2 * l + 1;
    const int tl = xlen[b], ul = ylen[b];
    const float NEG = -1e30f;
    const unsigned* lbu = (const unsigned*)lbp;
    const unsigned* lyu = (const unsigned*)lyp;
    float alpha0 = (l == 0) ? 0.f : NEG;
    float alpha1 = NEG;

    // prefetch for d=1
    int pt0 = 1 - u0, pt1 = 1 - u1;
    bool vb0 = (u0 <= UU && pt0 >= 1 && pt0 < TT);
    bool vy0 = (u0 >= 1 && u0 <= UU && pt0 >= 0 && pt0 < TT);
    bool vb1 = (u1 <= UU && pt1 >= 1 && pt1 < TT);
    bool vy1 = (u1 >= 1 && u1 <= UU && pt1 >= 0 && pt1 < TT);
    unsigned nb0 = vb0 ? ald32(lbu + ((size_t)b * TT + pt0 - 1) * UP1 + u0) : 1u;
    unsigned ny0 = vy0 ? ald32(lyu + ((size_t)b * TT + pt0) * UU + (u0 - 1)) : 1u;
    unsigned nb1 = vb1 ? ald32(lbu + ((size_t)b * TT + pt1 - 1) * UP1 + u1) : 1u;
    unsigned ny1 = vy1 ? ald32(lyu + ((size_t)b * TT + pt1) * UU + (u1 - 1)) : 1u;

    for (int d = 1; d <= TT - 1 + UU; d++) {
      // resolve tags for this diagonal
      {
        int tries = 0;
        for (;;) {
          unsigned m = nb0 & ny0 & nb1 & ny1;
          if (__all((int)(m & 1u)) || ++tries > (1 << 17)) break;
          if (tries > 8) __builtin_amdgcn_s_sleep(2);
          int t0 = d - u0, t1 = d - u1;
          if (vb0) nb0 = ald32(lbu + ((size_t)b * TT + t0 - 1) * UP1 + u0);
          if (vy0) ny0 = ald32(lyu + ((size_t)b * TT + t0) * UU + (u0 - 1));
          if (vb1) nb1 = ald32(lbu + ((size_t)b * TT + t1 - 1) * UP1 + u1);
          if (vy1) ny1 = ald32(lyu + ((size_t)b * TT + t1) * UU + (u1 - 1));
        }
      }
      float lb0 = vb0 ? __uint_as_float(nb0 & ~1u) : 0.f;
      float ly0 = vy0 ? __uint_as_float(ny0 & ~1u) : 0.f;
      float lb1 = vb1 ? __uint_as_float(nb1 & ~1u) : 0.f;
      float ly1 = vy1 ? __uint_as_float(ny1 & ~1u) : 0.f;
      // issue prefetch for d+1
      pt0 = (d + 1) - u0; pt1 = (d + 1) - u1;
      vb0 = (u0 <= UU && pt0 >= 1 && pt0 < TT);
      vy0 = (u0 >= 1 && u0 <= UU && pt0 >= 0 && pt0 < TT);
      vb1 = (u1 <= UU && pt1 >= 1 && pt1 < TT);
      vy1 = (u1 >= 1 && u1 <= UU && pt1 >= 0 && pt1 < TT);
      nb0 = vb0 ? ald32(lbu + ((size_t)b * TT + pt0 - 1) * UP1 + u0) : 1u;
      ny0 = vy0 ? ald32(lyu + ((size_t)b * TT + pt0) * UU + (u0 - 1)) : 1u;
      nb1 = vb1 ? ald32(lbu + ((size_t)b * TT + pt1 - 1) * UP1 + u1) : 1u;
      ny1 = vy1 ? ald32(lyu + ((size_t)b * TT + pt1) * UU + (u1 - 1)) : 1u;

      float am1 = __shfl_up(alpha1, 1);
      float old0 = alpha0, old1 = alpha1;
      int t0 = d - u0;
      if (u0 <= UU && t0 >= 0 && t0 < TT) {
        float a1 = (t0 >= 1) ? old0 + lb0 : NEG;
        float a2 = (u0 >= 1) ? am1 + ly0 : NEG;
        float m = fmaxf(a1, a2);
        float val = (m <= -1e29f) ? NEG : m + __logf(1.f + __expf(-fabsf(a1 - a2)));
        alpha0 = val;
        if (t0 == tl - 1 && u0 == ul) {
          unsigned lt; int tr = 0;
          for (;;) { lt = ald32(lbu + ((size_t)b * TT + t0) * UP1 + u0);
                     if ((lt & 1u) || ++tr > (1 << 17)) break;
                     __builtin_amdgcn_s_sleep(2); }
          atomicAdd(out, -0.125f * (val + __uint_as_float(lt & ~1u)));
        }
      }
      int t1 = d - u1;
      if (u1 <= UU && t1 >= 0 && t1 < TT) {
        float a1 = (t1 >= 1) ? old1 + lb1 : NEG;
        float a2 = old0 + ly1;                 // u1 odd => u1>=1 always
        float m = fmaxf(a1, a2);
        float val = (m <= -1e29f) ? NEG : m + __logf(1.f + __expf(-fabsf(a1 - a2)));
        alpha1 = val;
        if (t1 == tl - 1 && u1 == ul) {
          unsigned lt; int tr = 0;
          for (;;) { lt = ald32(lbu + ((size_t)b * TT + t1) * UP1 + u1);
                     if ((lt & 1u) || ++tr > (1 << 17)) break;
                     __builtin_amdgcn_s_sleep(2); }
          atomicAdd(out, -0.125f * (val + __uint_as_float(lt & ~1u)));
        }
      }
    }
    return;
  }

  if (wg == 24) {
    // ================= dec projection -> dec2 + done flag =================
    ushort* wl = (ushort*)wlds;
    for (int i = tid; i < 40960; i += 512) wl[i] = dwob[i];
    __syncthreads();
    const int nt = wave;
    const int vc = nt * 16 + n16;
    const float bias = dbo[vc];
    s8v bf[10];
#pragma unroll
    for (int kt = 0; kt < 10; kt++)
      bf[kt] = *(const s8v*)(wl + (size_t)vc * HH + kt * 32 + q * 8);
    for (int t = 0; t < UP1; t++) {
      const unsigned* src = hdu + (size_t)(t + 1) * 2560 + wave * 320 + lane;
      unsigned v[5];
#pragma unroll
      for (int j = 0; j < 5; j++) v[j] = ald32(src + j * 64);
      int tries = 0;
      for (;;) {
        unsigned a = v[0] & v[1] & v[2] & v[3] & v[4];
        if (__all((int)(a & 1u)) || ++tries > (1 << 17)) break;
        if (tries > 64) __builtin_amdgcn_s_sleep(1);
#pragma unroll
        for (int j = 0; j < 5; j++) v[j] = ald32(src + j * 64);
      }
#pragma unroll
      for (int j = 0; j < 5; j++) {
        int f = wave * 320 + j * 64 + lane;
        hbS[0][f & 7][f >> 3] = (ushort)(v[j] >> 16);
      }
      __syncthreads();
      s8v a[10];
#pragma unroll
      for (int kt = 0; kt < 10; kt++)
        a[kt] = *(const s8v*)&hbS[0][n16][kt * 32 + q * 8];
      f4v acc = {0.f, 0.f, 0.f, 0.f};
#pragma unroll
      for (int kt = 0; kt < 10; kt++)
        acc = __builtin_amdgcn_mfma_f32_16x16x32_bf16(a[kt], bf[kt], acc, 0, 0, 0);
      if (q < 2) {
#pragma unroll
        for (int r = 0; r < 4; r++) {
          int b = 4 * q + r;
          ast32((unsigned*)&dec2[((size_t)t * 16 + b) * VV + vc],
                __float_as_uint(acc[r] + bias));
        }
      }
      __syncthreads();
    }
    asm volatile("s_waitcnt vmcnt(0)" ::: "memory");
    __syncthreads();
    if (tid == 0) ast32(dflag, 1u);
    return;
  }

  if (wg >= 20) {
    // ================= enc projection + FUSED LSE =================
    const int tstart = wg - 20;              // stride 4
    ushort* wl = (ushort*)wlds;
    for (int i = tid; i < 40960; i += 512) wl[i] = wob[i];
    __syncthreads();
    const int nt = wave;
    const int vc = nt * 16 + n16;
    const float bias = ebo[vc];
    s8v bf[10];
#pragma unroll
    for (int kt = 0; kt < 10; kt++)
      bf[kt] = *(const s8v*)(wl + (size_t)vc * HH + kt * 32 + q * 8);
    const unsigned* d2u = (const unsigned*)dec2;
    const int ll = lane & 31;
    const int half = lane >> 5;
    bool decReady = false;

    for (int t = tstart; t < TT; t += 4) {
      // poll h1[t+1]
      const unsigned* src = h1u + (size_t)(t + 1) * 2560 + wave * 320 + lane;
      unsigned v[5];
#pragma unroll
      for (int j = 0; j < 5; j++) v[j] = ald32(src + j * 64);
      int tries = 0;
      for (;;) {
        unsigned a = v[0] & v[1] & v[2] & v[3] & v[4];
        if (__all((int)(a & 1u)) || ++tries > (1 << 17)) break;
        if (tries > 64) __builtin_amdgcn_s_sleep(1);
#pragma unroll
        for (int j = 0; j < 5; j++) v[j] = ald32(src + j * 64);
      }
#pragma unroll
      for (int j = 0; j < 5; j++) {
        int f = wave * 320 + j * 64 + lane;
        hbS[0][f & 7][f >> 3] = (ushort)(v[j] >> 16);
      }
      __syncthreads();
      s8v a[10];
#pragma unroll
      for (int kt = 0; kt < 10; kt++)
        a[kt] = *(const s8v*)&hbS[0][n16][kt * 32 + q * 8];
      f4v acc = {0.f, 0.f, 0.f, 0.f};
#pragma unroll
      for (int kt = 0; kt < 10; kt++)
        acc = __builtin_amdgcn_mfma_f32_16x16x32_bf16(a[kt], bf[kt], acc, 0, 0, 0);
      if (q < 2) {
#pragma unroll
        for (int r = 0; r < 4; r++) encL[4 * q + r][vc] = acc[r] + bias;
      }
      // gate once on dec2 completion (flag set by wg24 after full drain)
      if (!decReady) {
        int tr = 0;
        for (;;) {
          if (ald32(dflag) & 1u) break;
          if (++tr > (1 << 17)) break;
          __builtin_amdgcn_s_sleep(16);
        }
        decReady = true;
      }
      __syncthreads();                       // encL visible

      // ---- fused lse: 2 pairs/wave/slot, depth-4 pipelined IC reads ----
      unsigned r0[4], r1[4], r2[4], r3[4];
      LSE_ISSUE(r0, 0) LSE_ISSUE(r1, 1) LSE_ISSUE(r2, 2) LSE_ISSUE(r3, 3)
      for (int io = 0; io < 16; io++) {
        const int i4 = io * 4;
        LSE_PROC(r0, i4 + 0) LSE_ISSUE(r0, i4 + 4)
        LSE_PROC(r1, i4 + 1) LSE_ISSUE(r1, i4 + 5)
        LSE_PROC(r2, i4 + 2) LSE_ISSUE(r2, i4 + 6)
        LSE_PROC(r3, i4 + 3) LSE_ISSUE(r3, i4 + 7)
      }
      __syncthreads();                       // protect encL/hbS for next t
    }
    return;
  }

  if (wg >= 15) {
    // ================= relay: xp1[s] = Wih1 @ h0[s+1] + b1 =================
    const int rw = wg - 15;
    const int w = rw * 8 + wave;
    const int ubase = w * 8;
    const ushort* Win = wb + 409600;         // Wih1
    s8v afr0[10];
    {
      const int arow0 = g * HH + ubase + uloc;
      const int arow1 = g * HH + ubase + 4 + uloc;
#pragma unroll
      for (int kt = 0; kt < 10; kt++) {
        afr0[kt] = *(const s8v*)(Win + arow0 * HH + kt * 32 + q * 8);
        wlds[wave][kt][lane] = *(const s8v*)(Win + arow1 * HH + kt * 32 + q * 8);
      }
    }
    f4v bias4[2];
#pragma unroll
    for (int tile = 0; tile < 2; tile++)
      bias4[tile] = *(const f4v*)(b1p + (ubase + tile * 4 + q) * 4);

    unsigned v[5];
    {
      const unsigned* p = h0u + 2560 + wave * 320 + lane;
#pragma unroll
      for (int j = 0; j < 5; j++) v[j] = ald32(p + j * 64);
    }
    __syncthreads();

    for (int s = 0; s < TT; s++) {
      const int pb = s & 1;
      {
        const unsigned* p = h0u + (size_t)(s + 1) * 2560 + wave * 320 + lane;
        int tries = 0;
        for (;;) {
          unsigned a = v[0] & v[1] & v[2] & v[3] & v[4];
          if (__all((int)(a & 1u)) || ++tries > (1 << 17)) break;
          if (tries > 64) __builtin_amdgcn_s_sleep(1);
#pragma unroll
          for (int j = 0; j < 5; j++) v[j] = ald32(p + j * 64);
        }
#pragma unroll
        for (int j = 0; j < 5; j++) {
          int f = wave * 320 + j * 64 + lane;
          hbS[pb][f & 7][f >> 3] = (ushort)(v[j] >> 16);
        }
      }
      __syncthreads();
      if (s + 1 < TT) {
        const unsigned* p = h0u + (size_t)(s + 2) * 2560 + wave * 320 + lane;
#pragma unroll
        for (int j = 0; j < 5; j++) v[j] = ald32(p + j * 64);
      }

      f4v acc[2];
      acc[0] = bias4[0]; acc[1] = bias4[1];
#pragma unroll
      for (int kt = 0; kt < 10; kt++) {
        s8v b = *(const s8v*)&hbS[pb][n16][kt * 32 + q * 8];
        acc[0] = __builtin_amdgcn_mfma_f32_16x16x32_bf16(afr0[kt], b, acc[0], 0, 0, 0);
        s8v a1 = wlds[wave][kt][lane];
        acc[1] = __builtin_amdgcn_mfma_f32_16x16x32_bf16(a1, b, acc[1], 0, 0, 0);
      }
      if (act) {
#pragma unroll
        for (int tile = 0; tile < 2; tile++) {
          unsigned* dp = xp1u + (size_t)((unsigned)s * 8u + (unsigned)n16) * G4
                       + (unsigned)((ubase + tile * 4 + q) * 4);
#pragma unroll
          for (int r = 0; r < 4; r++)
            ast32(dp + r, __float_as_uint(acc[tile][r]) | 1u);   // LSB tag on f32
        }
      }
    }
    return;
  }

  // ================= recurrent stages =================
  const int stage = wg / 5;
  const int gw = wg - stage * 5;
  const int w = gw * 8 + wave;              // wave-in-stage [0,40)
  const int ubase = w * 8;                  // this wave owns units [ubase, ubase+8)

  const ushort* A = wb + (stage == 0 ? 0 : (stage == 1 ? 819200 : 1228800));
  // tile0 -> regs (40 VGPR), tile1 -> LDS
  s8v afr0[10];
  {
    const int arow0 = g * HH + ubase + uloc;
    const int arow1 = g * HH + ubase + 4 + uloc;
#pragma unroll
    for (int kt = 0; kt < 10; kt++) {
      afr0[kt] = *(const s8v*)(A + arow0 * HH + kt * 32 + q * 8);
      wlds[wave][kt][lane] = *(const s8v*)(A + arow1 * HH + kt * 32 + q * 8);
    }
  }

  const int steps = (stage == 2) ? UP1 : TT;
  unsigned* hio = (stage == 0) ? h0u : ((stage == 1) ? h1u : hdu);

  const float* xq = 0;
  if (stage == 0)      xq = xp0 + (size_t)bcol * TT * G4;
  else if (stage == 2) xq = xpd + (size_t)bcol * UP1 * G4;

  float c0 = 0.f, c1 = 0.f;
  unsigned hv5[5];                           // in-flight bulk h reads
  __syncthreads();                           // LDS zeros + weight-LDS visible

  for (int t = 0; t < steps; t++) {
    const int pb = t & 1;

    // ---- pre-issue C-init inputs; consumed after the MFMA block ----
    f4v xq4[2];
    unsigned xv[2][4];
    if (stage != 1) {
#pragma unroll
      for (int tile = 0; tile < 2; tile++)
        xq4[tile] = *(const f4v*)(xq + (size_t)t * G4 + (ubase + tile * 4 + q) * 4);
    } else {
#pragma unroll
      for (int tile = 0; tile < 2; tile++) {
        const unsigned* xpp = xp1u + (size_t)((unsigned)t * 8u + (unsigned)bcol) * G4
                            + (unsigned)((ubase + tile * 4 + q) * 4);
#pragma unroll
        for (int r = 0; r < 4; r++) xv[tile][r] = ald32(xpp + r);
      }
    }

    // ---- resolve pre-issued bulk h[t] reads, transpose-relay into LDS ----
    if (t > 0) {
      const unsigned* src = hio + (size_t)t * 2560 + wave * 320 + lane;
      int tries = 0;
      for (;;) {
        unsigned a = hv5[0] & hv5[1] & hv5[2] & hv5[3] & hv5[4];
        if (__all((int)(a & 1u)) || ++tries > (1 << 17)) break;
        if (tries > 64) __builtin_amdgcn_s_sleep(1);
#pragma unroll
        for (int j = 0; j < 5; j++) hv5[j] = ald32(src + j * 64);
      }
#pragma unroll
      for (int j = 0; j < 5; j++) {
        int f = wave * 320 + j * 64 + lane;            // u = f>>3, b = f&7
        hbS[pb][f & 7][f >> 3] = (ushort)(hv5[j] >> 16);
      }
    }
    __syncthreads();

    // ---- MFMAs: B-frags from LDS h(t); tile1 A-frags from LDS ----
    f4v acc[2];
    acc[0] = (f4v){0.f, 0.f, 0.f, 0.f};
    acc[1] = (f4v){0.f, 0.f, 0.f, 0.f};
#pragma unroll
    for (int kt = 0; kt < 10; kt++) {
      s8v b = *(const s8v*)&hbS[pb][n16][kt * 32 + q * 8];
      acc[0] = __builtin_amdgcn_mfma_f32_16x16x32_bf16(afr0[kt], b, acc[0], 0, 0, 0);
      s8v a1 = wlds[wave][kt][lane];
      acc[1] = __builtin_amdgcn_mfma_f32_16x16x32_bf16(a1, b, acc[1], 0, 0, 0);
    }

    // ---- resolve C-init (deferred add; stage1 tag-spins on relay output) ----
    if (stage != 1) {
#pragma unroll
      for (int tile = 0; tile < 2; tile++) {
        acc[tile][0] += xq4[tile][0]; acc[tile][1] += xq4[tile][1];
        acc[tile][2] += xq4[tile][2]; acc[tile][3] += xq4[tile][3];
      }
    } else {
      int tries = 0;
      for (;;) {
        unsigned m = xv[0][0] & xv[0][1] & xv[0][2] & xv[0][3]
                   & xv[1][0] & xv[1][1] & xv[1][2] & xv[1][3];
        bool ok = (!act) || ((m & 1u) != 0u);
        if (__all((int)ok) || ++tries > (1 << 17)) break;
        if (tries > 64) __builtin_amdgcn_s_sleep(1);
#pragma unroll
        for (int tile = 0; tile < 2; tile++) {
          const unsigned* xpp = xp1u + (size_t)((unsigned)t * 8u + (unsigned)bcol) * G4
                              + (unsigned)((ubase + tile * 4 + q) * 4);
#pragma unroll
          for (int r = 0; r < 4; r++) xv[tile][r] = ald32(xpp + r);
        }
      }
#pragma unroll
      for (int tile = 0; tile < 2; tile++)
#pragma unroll
        for (int r = 0; r < 4; r++)
          acc[tile][r] += __uint_as_float(xv[tile][r] & ~1u);
    }

    // ---- lane-local LSTM cell ----
    float hv0, hv1;
    {
      float ig = sigf(acc[0][0]), fg = sigf(acc[0][1]);
      float gv = tanh_f(acc[0][2]), og = sigf(acc[0][3]);
      c0 = fg * c0 + ig * gv; hv0 = og * tanh_f(c0);
    }
    {
      float ig = sigf(acc[1][0]), fg = sigf(acc[1][1]);
      float gv = tanh_f(acc[1][2]), og = sigf(acc[1][3]);
      c1 = fg * c1 + ig * gv; hv1 = og * tanh_f(c1);
    }
    if (act) {
      // packed [u][b] store: wave's 16 stores span 2-4 cache lines; no drain
      unsigned* dst = hio + (size_t)(t + 1) * 2560;
      ast32(dst + (ubase + q) * 8 + n16,     (((unsigned)f2bf(hv0)) << 16) | 1u);
      ast32(dst + (ubase + 4 + q) * 8 + n16, (((unsigned)f2bf(hv1)) << 16) | 1u);
    }

    // ---- issue next step's bulk h reads: flight overlaps store landing ----
    if (t + 1 < steps) {
      const unsigned* src = hio + (size_t)(t + 1) * 2560 + wave * 320 + lane;
#pragma unroll
      for (int j = 0; j < 5; j++) hv5[j] = ald32(src + j * 64);
    }
  }
}

// ---------------- launch ----------------
extern "C" void kernel_launch(void* const* d_in, const int* in_sizes, int n_in,
                              void* d_out, int out_size, void* d_ws, size_t ws_size,
                              hipStream_t stream) {
  (void)in_sizes; (void)n_in; (void)out_size;
  const float* xs    = (const float*)d_in[0];
  const int*   ys    = (const int*)d_in[1];
  const int*   xlen  = (const int*)d_in[2];
  const int*   ylen  = (const int*)d_in[3];
  const float* eWih0 = (const float*)d_in[4];
  const float* eWhh0 = (const float*)d_in[5];
  const float* ebih0 = (const float*)d_in[6];
  const float* ebhh0 = (const float*)d_in[7];
  const float* eWih1 = (const float*)d_in[8];
  const float* eWhh1 = (const float*)d_in[9];
  const float* ebih1 = (const float*)d_in[10];
  const float* ebhh1 = (const float*)d_in[11];
  const float* eWo   = (const float*)d_in[12];
  const float* ebo   = (const float*)d_in[13];
  const float* dWih  = (const float*)d_in[15];
  const float* dWhh  = (const float*)d_in[16];
  const float* dbih  = (const float*)d_in[17];
  const float* dbhh  = (const float*)d_in[18];
  const float* dWo   = (const float*)d_in[19];
  const float* dbo   = (const float*)d_in[20];

  char* ws = (char*)d_ws;
  const size_t OFF_XP0   = 1024;
  const size_t OFF_XPD   = OFF_XP0   + 20480000;  // 8*500*1280 f32
  const size_t OFF_H0    = OFF_XPD   + 4956160;   // 501 * 2560 u32 (tagged, [u][b])
  const size_t OFF_H1    = OFF_H0    + 5130240;
  const size_t OFF_HD    = OFF_H1    + 5130240;   // 122 * 2560 u32
  const size_t OFF_WB    = OFF_HD    + 1249280;
  const size_t OFF_WIH0B = OFF_WB    + 3276800;   // 4*1280*320 bf16
  const size_t OFF_XSB   = OFF_WIH0B + 245760;    // 1280*96 bf16
  const size_t OFF_WOB   = OFF_XSB   + 768000;    // 4000*96 bf16
  const size_t OFF_DWOB  = OFF_WOB   + 81920;
  const size_t OFF_B1P   = OFF_DWOB  + 81920;
  const size_t OFF_B0S   = OFF_B1P   + 5120;
  const size_t OFF_ENC2  = OFF_B0S   + 5120;      // (unused this round)
  const size_t OFF_DEC2  = OFF_ENC2  + 4096000;   // 121*16*128 f32 (agent-scope)
  const size_t OFF_LB    = OFF_DEC2  + 991232;    // 8*500*121 tagged f32
  const size_t OFF_LY    = OFF_LB    + 1936000;   // 8*500*120 tagged f32
  const size_t OFF_XP1   = OFF_LY    + 1920000;   // 500*8*1280 tagged f32
  const size_t OFF_FLAG  = OFF_XP1   + 20480000;  // dec2-done flag
  const size_t TOTAL     = OFF_FLAG  + 64;
  if (ws_size < TOTAL) return;

  float*    xp0   = (float*)(ws + OFF_XP0);
  float*    xpd   = (float*)(ws + OFF_XPD);
  unsigned* h0    = (unsigned*)(ws + OFF_H0);
  unsigned* h1    = (unsigned*)(ws + OFF_H1);
  unsigned* hd    = (unsigned*)(ws + OFF_HD);
  ushort*   wb    = (ushort*)(ws + OFF_WB);
  ushort*   wih0b = (ushort*)(ws + OFF_WIH0B);
  ushort*   xsb   = (ushort*)(ws + OFF_XSB);
  ushort*   wob   = (ushort*)(ws + OFF_WOB);
  ushort*   dwob  = (ushort*)(ws + OFF_DWOB);
  float*    b1p   = (float*)(ws + OFF_B1P);
  float*    b0s   = (float*)(ws + OFF_B0S);
  float*    dec2  = (float*)(ws + OFF_DEC2);
  float*    lb    = (float*)(ws + OFF_LB);
  float*    ly    = (float*)(ws + OFF_LY);
  unsigned* xp1   = (unsigned*)(ws + OFF_XP1);
  unsigned* dflag = (unsigned*)(ws + OFF_FLAG);
  float*    out   = (float*)d_out;

  hipLaunchKernelGGL(prep_zero, dim3(1), dim3(64), 0, stream, out);
  hipLaunchKernelGGL(prep_w, dim3(8710), dim3(256), 0, stream,
                     eWhh0, eWih1, eWhh1, dWhh, eWih0, xs, eWo, dWo,
                     ebih1, ebhh1, ebih0, ebhh0,
                     wb, wih0b, xsb, wob, dwob, b1p, b0s);
  hipLaunchKernelGGL(xproj0_mfma, dim3(250), dim3(256), 0, stream, xsb, wih0b, b0s, xp0);
  hipLaunchKernelGGL(xprojd_g, dim3(968), dim3(256), 0, stream, ys, dWih, dbih, dbhh, xpd);
  hipLaunchKernelGGL(lstm_fused, dim3(26), dim3(512), 0, stream,
                     wb, b1p, xp0, xpd, h0, h1, hd, xp1,
                     wob, dwob, ebo, dbo, dec2, lb, ly,
                     ys, xlen, ylen, out, dflag);
}

// Round 12
// 2063.279 us; speedup vs baseline: 2.9893x; 2.9893x over previous
//
#include <hip/hip_runtime.h>

typedef __attribute__((ext_vector_type(8))) short s8v;   // 8 x bf16 (4 VGPRs)
typedef __attribute__((ext_vector_type(4))) float f4v;   // MFMA accumulator

#define BB 8
#define TT 500
#define UU 120
#define UP1 121
#define VV 128
#define HH 320
#define G4 1280

// ---------------- helpers ----------------
__device__ __forceinline__ unsigned short f2bf(float x) {
  unsigned u = __builtin_bit_cast(unsigned, x);
  unsigned r = (u + 0x7FFFu + ((u >> 16) & 1u)) >> 16;  // RNE
  return (unsigned short)r;
}
__device__ __forceinline__ s8v ld8bf(const float* p) {  // 8 f32 -> s8v bf16
  s8v r;
#pragma unroll
  for (int j = 0; j < 8; j++) r[j] = (short)f2bf(p[j]);
  return r;
}
__device__ __forceinline__ float sigf(float x)   { return 1.f / (1.f + __expf(-x)); }
__device__ __forceinline__ float tanh_f(float x) { return 2.f / (1.f + __expf(-2.f * x)) - 1.f; }

// agent-scope (L3-coherent) relaxed atomics — proven transport
__device__ __forceinline__ unsigned ald32(const unsigned* p) {
  return __hip_atomic_load((unsigned*)p, __ATOMIC_RELAXED, __HIP_MEMORY_SCOPE_AGENT);
}
__device__ __forceinline__ void ast32(unsigned* p, unsigned v) {
  __hip_atomic_store(p, v, __ATOMIC_RELAXED, __HIP_MEMORY_SCOPE_AGENT);
}

// ---------------- prep: conversions + bias folds + xprojd + out-zero ----------------
// blocks [0, 1990): wih0b / xsb / b1p / b0s conversions (509440 elements)
// blocks [1990, 2958): decoder input projection (one-hot gather), 968 blocks
__global__ __launch_bounds__(256) void prep_w(
    const float* __restrict__ wih0, const float* __restrict__ xs,
    const float* __restrict__ bih1, const float* __restrict__ bhh1,
    const float* __restrict__ bih0, const float* __restrict__ bhh0,
    const int* __restrict__ ys, const float* __restrict__ dWih,
    const float* __restrict__ dbih, const float* __restrict__ dbhh,
    ushort* __restrict__ wih0b, ushort* __restrict__ xsb,
    float* __restrict__ bias1p, float* __restrict__ b0s,
    float* __restrict__ xpd, float* __restrict__ out)
{
  if (blockIdx.x >= 1990) {                  // ---- xprojd section ----
    const int blk = blockIdx.x - 1990;       // 968 = 8 * 121
    const int b = blk / UP1, u = blk - b * UP1;
    int colv = -1;
    if (u > 0) colv = ys[b * UU + (u - 1)] - 1;
    for (int i = threadIdx.x; i < G4; i += 256) {
      int uu = i >> 2, gg = i & 3;
      int row = gg * HH + uu;
      float v = dbih[row] + dbhh[row];
      if (colv >= 0) v += dWih[row * 127 + colv];
      xpd[((size_t)b * UP1 + u) * G4 + i] = v;
    }
    return;
  }
  int i = blockIdx.x * blockDim.x + threadIdx.x;
  if (i == 0) out[0] = 0.f;
  if (i < 122880) {                          // Wih0 [1280][80] -> [1280][96] padded
    int row = i / 96, k = i - row * 96;
    wih0b[i] = (k < 80) ? f2bf(wih0[row * 80 + k]) : (ushort)0;
  } else if (i < 506880) {                   // xs [4000][80] -> [4000][96] padded
    int e = i - 122880;
    int row = e / 96, k = e - row * 96;
    xsb[e] = (k < 80) ? f2bf(xs[row * 80 + k]) : (ushort)0;
  } else if (i < 508160) {                   // bias1 permuted [unit][gate]
    int e = i - 506880;
    int uq = e >> 2, gq = e & 3;
    bias1p[e] = bih1[gq * HH + uq] + bhh1[gq * HH + uq];
  } else if (i < 509440) {                   // bih0+bhh0 summed (gate-row order)
    int e = i - 508160;
    b0s[e] = bih0[e] + bhh0[e];
  }
}

// ---------------- xproj for layer0: [4000,96]bf16 @ [96,1280] -> xp0[b][t][u][g] f32 ----------------
__global__ __launch_bounds__(256) void xproj0_mfma(
    const ushort* __restrict__ xsb, const ushort* __restrict__ wih0b,
    const float* __restrict__ b0s, float* __restrict__ xp0)
{
  const int mt = blockIdx.x;                 // 250 tiles of 16 (b,t)-rows
  const int wave = threadIdx.x >> 6, lane = threadIdx.x & 63;
  const int q = lane >> 4, n16 = lane & 15;
  s8v a[3];
#pragma unroll
  for (int kt = 0; kt < 3; kt++)
    a[kt] = *(const s8v*)(xsb + (mt * 16 + n16) * 96 + kt * 32 + q * 8);
  for (int nt = wave; nt < 80; nt += 4) {
    s8v bf[3];
#pragma unroll
    for (int kt = 0; kt < 3; kt++)
      bf[kt] = *(const s8v*)(wih0b + (nt * 16 + n16) * 96 + kt * 32 + q * 8);
    f4v acc = {0.f, 0.f, 0.f, 0.f};
#pragma unroll
    for (int kt = 0; kt < 3; kt++)
      acc = __builtin_amdgcn_mfma_f32_16x16x32_bf16(a[kt], bf[kt], acc, 0, 0, 0);
    const int gr = nt * 16 + n16;            // D col = gate row
    const int gg = gr / HH;
    const int uu = gr - gg * HH;
    const float bias = b0s[gr];
#pragma unroll
    for (int r = 0; r < 4; r++) {
      int bt = mt * 16 + 4 * q + r;          // D row = (b,t) row
      xp0[(size_t)bt * G4 + uu * 4 + gg] = acc[r] + bias;
    }
  }
}

// ======================================================================
// Fused recurrences v9 = R9 structure (proven 1507us) with INLINE weight
// conversion (stage/relay/proj WGs read f32 weights directly, f2bf while
// building fragments — bit-identical, deletes prep_w's 1.64M-element
// section). 24 WGs x 512 thr:
//   wg 0-4  : stage0, wg 5-9: stage1, wg 10-14: dec
//   wg 15-19: relay xp1 = Wih1@h0[s+1] + b1
//   wg 20-22: enc proj streaming (t stride 3), wg 23: dec proj.
// Transport: direct bulk tag-poll (R8-proven), packed h [t][u][b],
// tile0-in-regs + tile1-in-LDS weights, deferred C-init resolve.
// ======================================================================
__global__ __launch_bounds__(512, 1) void lstm_fused(
    const float* __restrict__ eWhh0, const float* __restrict__ eWih1,
    const float* __restrict__ eWhh1, const float* __restrict__ dWhh,
    const float* __restrict__ b1p,
    const float* __restrict__ xp0, const float* __restrict__ xpd,
    unsigned* __restrict__ h0u, unsigned* __restrict__ h1u, unsigned* __restrict__ hdu,
    unsigned* __restrict__ xp1u,
    const float* __restrict__ eWo, const float* __restrict__ dWo,
    const float* __restrict__ ebo, const float* __restrict__ dbo,
    float* __restrict__ enc2, float* __restrict__ dec2)
{
  __shared__ ushort hbS[2][16][328];         // 21KB  h double-buffer [b][u]
  __shared__ s8v wlds[8][10][64];            // 80KB  tile1 weight frags / proj Wo

  const int wg = blockIdx.x;
  const int tid = threadIdx.x;
  const int wave = tid >> 6, lane = tid & 63;
  const int q = lane >> 4, n16 = lane & 15;
  const int uloc = n16 >> 2, g = n16 & 3;
  const int bcol = n16 & 7;
  const bool act = (n16 < BB);

  // zero both LDS h buffers (t=0 state = zeros; rows 8..15 stay zero forever)
  for (int i = tid; i < 2 * 16 * 328; i += 512) ((ushort*)hbS)[i] = 0;

  if (wg >= 20) {
    // ================= streaming output projections =================
    const bool isenc = (wg < 23);
    const unsigned* hsrc = isenc ? h1u : hdu;
    const float* wsrc = isenc ? eWo : dWo;   // f32, converted on stage-in
    const float* bsrc = isenc ? ebo : dbo;
    float* osrc = isenc ? enc2 : dec2;
    const int tstart = isenc ? (wg - 20) : 0;
    const int tstep = isenc ? 3 : 1;
    const int tmax = isenc ? TT : UP1;
    // stage Wo [128][320] into the 80KB wlds region as bf16 (exact fit)
    ushort* wl = (ushort*)wlds;
    for (int i = tid; i < 40960; i += 512) wl[i] = f2bf(wsrc[i]);
    __syncthreads();
    const int nt = wave;                     // 8 col-tiles of 16
    const int vc = nt * 16 + n16;
    const float bias = bsrc[vc];
    s8v bf[10];
#pragma unroll
    for (int kt = 0; kt < 10; kt++)
      bf[kt] = *(const s8v*)(wl + (size_t)vc * HH + kt * 32 + q * 8);

    for (int t = tstart; t < tmax; t += tstep) {
      // bulk tagged read of h[t+1] (flat 2560, 8 waves x 320)
      const unsigned* src = hsrc + (size_t)(t + 1) * 2560 + wave * 320 + lane;
      unsigned v[5];
#pragma unroll
      for (int j = 0; j < 5; j++) v[j] = ald32(src + j * 64);
      int tries = 0;
      for (;;) {
        unsigned a = v[0] & v[1] & v[2] & v[3] & v[4];
        if (__all((int)(a & 1u)) || ++tries > (1 << 17)) break;
        if (tries > 64) __builtin_amdgcn_s_sleep(1);
#pragma unroll
        for (int j = 0; j < 5; j++) v[j] = ald32(src + j * 64);
      }
#pragma unroll
      for (int j = 0; j < 5; j++) {
        int f = wave * 320 + j * 64 + lane;            // u = f>>3, b = f&7
        hbS[0][f & 7][f >> 3] = (ushort)(v[j] >> 16);
      }
      __syncthreads();
      s8v a[10];
#pragma unroll
      for (int kt = 0; kt < 10; kt++)
        a[kt] = *(const s8v*)&hbS[0][n16][kt * 32 + q * 8];
      f4v acc = {0.f, 0.f, 0.f, 0.f};
#pragma unroll
      for (int kt = 0; kt < 10; kt++)
        acc = __builtin_amdgcn_mfma_f32_16x16x32_bf16(a[kt], bf[kt], acc, 0, 0, 0);
      if (q < 2) {
#pragma unroll
        for (int r = 0; r < 4; r++) {
          int b = 4 * q + r;                 // D row = batch
          osrc[((size_t)t * 16 + b) * VV + vc] = acc[r] + bias;
        }
      }
      __syncthreads();                       // before next t overwrites hbS
    }
    return;
  }

  if (wg >= 15) {
    // ================= relay: xp1[s] = Wih1 @ h0[s+1] + b1 =================
    const int rw = wg - 15;
    const int w = rw * 8 + wave;
    const int ubase = w * 8;
    s8v afr0[10];
    {
      const int arow0 = g * HH + ubase + uloc;
      const int arow1 = g * HH + ubase + 4 + uloc;
#pragma unroll
      for (int kt = 0; kt < 10; kt++) {
        afr0[kt] = ld8bf(eWih1 + (size_t)arow0 * HH + kt * 32 + q * 8);
        wlds[wave][kt][lane] = ld8bf(eWih1 + (size_t)arow1 * HH + kt * 32 + q * 8);
      }
    }
    f4v bias4[2];
#pragma unroll
    for (int tile = 0; tile < 2; tile++)
      bias4[tile] = *(const f4v*)(b1p + (ubase + tile * 4 + q) * 4);

    // pre-issue h0[1] bulk loads
    unsigned v[5];
    {
      const unsigned* p = h0u + 2560 + wave * 320 + lane;
#pragma unroll
      for (int j = 0; j < 5; j++) v[j] = ald32(p + j * 64);
    }
    __syncthreads();                         // weight-LDS + hbS zeros visible

    for (int s = 0; s < TT; s++) {
      const int pb = s & 1;
      // resolve pre-issued h0[s+1] reads (retry on tag miss)
      {
        const unsigned* p = h0u + (size_t)(s + 1) * 2560 + wave * 320 + lane;
        int tries = 0;
        for (;;) {
          unsigned a = v[0] & v[1] & v[2] & v[3] & v[4];
          if (__all((int)(a & 1u)) || ++tries > (1 << 17)) break;
          if (tries > 64) __builtin_amdgcn_s_sleep(1);
#pragma unroll
          for (int j = 0; j < 5; j++) v[j] = ald32(p + j * 64);
        }
#pragma unroll
        for (int j = 0; j < 5; j++) {
          int f = wave * 320 + j * 64 + lane;          // u = f>>3, b = f&7
          hbS[pb][f & 7][f >> 3] = (ushort)(v[j] >> 16);
        }
      }
      __syncthreads();
      // issue next step's bulk loads now; flight hides under MFMA + stores
      if (s + 1 < TT) {
        const unsigned* p = h0u + (size_t)(s + 2) * 2560 + wave * 320 + lane;
#pragma unroll
        for (int j = 0; j < 5; j++) v[j] = ald32(p + j * 64);
      }

      f4v acc[2];
      acc[0] = bias4[0]; acc[1] = bias4[1];
#pragma unroll
      for (int kt = 0; kt < 10; kt++) {
        s8v b = *(const s8v*)&hbS[pb][n16][kt * 32 + q * 8];
        acc[0] = __builtin_amdgcn_mfma_f32_16x16x32_bf16(afr0[kt], b, acc[0], 0, 0, 0);
        s8v a1 = wlds[wave][kt][lane];
        acc[1] = __builtin_amdgcn_mfma_f32_16x16x32_bf16(a1, b, acc[1], 0, 0, 0);
      }
      if (act) {
#pragma unroll
        for (int tile = 0; tile < 2; tile++) {
          unsigned* dp = xp1u + (size_t)((unsigned)s * 8u + (unsigned)n16) * G4
                       + (unsigned)((ubase + tile * 4 + q) * 4);
#pragma unroll
          for (int r = 0; r < 4; r++)
            ast32(dp + r, __float_as_uint(acc[tile][r]) | 1u);   // LSB tag on f32
        }
      }
    }
    return;
  }

  // ================= recurrent stages =================
  const int stage = wg / 5;
  const int gw = wg - stage * 5;
  const int w = gw * 8 + wave;              // wave-in-stage [0,40)
  const int ubase = w * 8;                  // this wave owns units [ubase, ubase+8)

  const float* Af = (stage == 0) ? eWhh0 : ((stage == 1) ? eWhh1 : dWhh);
  // tile0 -> regs (40 VGPR), tile1 -> LDS; converted inline from f32
  s8v afr0[10];
  {
    const int arow0 = g * HH + ubase + uloc;
    const int arow1 = g * HH + ubase + 4 + uloc;
#pragma unroll
    for (int kt = 0; kt < 10; kt++) {
      afr0[kt] = ld8bf(Af + (size_t)arow0 * HH + kt * 32 + q * 8);
      wlds[wave][kt][lane] = ld8bf(Af + (size_t)arow1 * HH + kt * 32 + q * 8);
    }
  }

  const int steps = (stage == 2) ? UP1 : TT;
  unsigned* hio = (stage == 0) ? h0u : ((stage == 1) ? h1u : hdu);

  const float* xq = 0;
  if (stage == 0)      xq = xp0 + (size_t)bcol * TT * G4;
  else if (stage == 2) xq = xpd + (size_t)bcol * UP1 * G4;

  float c0 = 0.f, c1 = 0.f;
  unsigned hv5[5];                           // in-flight bulk h reads
  __syncthreads();                           // LDS zeros + weight-LDS visible

  for (int t = 0; t < steps; t++) {
    const int pb = t & 1;

    // ---- pre-issue C-init inputs; consumed after the MFMA block ----
    f4v xq4[2];
    unsigned xv[2][4];
    if (stage != 1) {
#pragma unroll
      for (int tile = 0; tile < 2; tile++)
        xq4[tile] = *(const f4v*)(xq + (size_t)t * G4 + (ubase + tile * 4 + q) * 4);
    } else {
#pragma unroll
      for (int tile = 0; tile < 2; tile++) {
        const unsigned* xpp = xp1u + (size_t)((unsigned)t * 8u + (unsigned)bcol) * G4
                            + (unsigned)((ubase + tile * 4 + q) * 4);
#pragma unroll
        for (int r = 0; r < 4; r++) xv[tile][r] = ald32(xpp + r);
      }
    }

    // ---- resolve pre-issued bulk h[t] reads, transpose-relay into LDS ----
    if (t > 0) {
      const unsigned* src = hio + (size_t)t * 2560 + wave * 320 + lane;
      int tries = 0;
      for (;;) {
        unsigned a = hv5[0] & hv5[1] & hv5[2] & hv5[3] & hv5[4];
        if (__all((int)(a & 1u)) || ++tries > (1 << 17)) break;
        if (tries > 64) __builtin_amdgcn_s_sleep(1);
#pragma unroll
        for (int j = 0; j < 5; j++) hv5[j] = ald32(src + j * 64);
      }
#pragma unroll
      for (int j = 0; j < 5; j++) {
        int f = wave * 320 + j * 64 + lane;            // u = f>>3, b = f&7
        hbS[pb][f & 7][f >> 3] = (ushort)(hv5[j] >> 16);
      }
    }
    __syncthreads();

    // ---- MFMAs: B-frags from LDS h(t); tile1 A-frags from LDS ----
    f4v acc[2];
    acc[0] = (f4v){0.f, 0.f, 0.f, 0.f};
    acc[1] = (f4v){0.f, 0.f, 0.f, 0.f};
#pragma unroll
    for (int kt = 0; kt < 10; kt++) {
      s8v b = *(const s8v*)&hbS[pb][n16][kt * 32 + q * 8];
      acc[0] = __builtin_amdgcn_mfma_f32_16x16x32_bf16(afr0[kt], b, acc[0], 0, 0, 0);
      s8v a1 = wlds[wave][kt][lane];
      acc[1] = __builtin_amdgcn_mfma_f32_16x16x32_bf16(a1, b, acc[1], 0, 0, 0);
    }

    // ---- resolve C-init (deferred add; stage1 tag-spins on relay output) ----
    if (stage != 1) {
#pragma unroll
      for (int tile = 0; tile < 2; tile++) {
        acc[tile][0] += xq4[tile][0]; acc[tile][1] += xq4[tile][1];
        acc[tile][2] += xq4[tile][2]; acc[tile][3] += xq4[tile][3];
      }
    } else {
      int tries = 0;
      for (;;) {
        unsigned m = xv[0][0] & xv[0][1] & xv[0][2] & xv[0][3]
                   & xv[1][0] & xv[1][1] & xv[1][2] & xv[1][3];
        bool ok = (!act) || ((m & 1u) != 0u);
        if (__all((int)ok) || ++tries > (1 << 17)) break;
        if (tries > 64) __builtin_amdgcn_s_sleep(1);
#pragma unroll
        for (int tile = 0; tile < 2; tile++) {
          const unsigned* xpp = xp1u + (size_t)((unsigned)t * 8u + (unsigned)bcol) * G4
                              + (unsigned)((ubase + tile * 4 + q) * 4);
#pragma unroll
          for (int r = 0; r < 4; r++) xv[tile][r] = ald32(xpp + r);
        }
      }
#pragma unroll
      for (int tile = 0; tile < 2; tile++)
#pragma unroll
        for (int r = 0; r < 4; r++)
          acc[tile][r] += __uint_as_float(xv[tile][r] & ~1u);
    }

    // ---- lane-local LSTM cell ----
    float hv0, hv1;
    {
      float ig = sigf(acc[0][0]), fg = sigf(acc[0][1]);
      float gv = tanh_f(acc[0][2]), og = sigf(acc[0][3]);
      c0 = fg * c0 + ig * gv; hv0 = og * tanh_f(c0);
    }
    {
      float ig = sigf(acc[1][0]), fg = sigf(acc[1][1]);
      float gv = tanh_f(acc[1][2]), og = sigf(acc[1][3]);
      c1 = fg * c1 + ig * gv; hv1 = og * tanh_f(c1);
    }
    if (act) {
      // packed [u][b] store: wave's 16 stores span 2-4 cache lines; no drain
      unsigned* dst = hio + (size_t)(t + 1) * 2560;
      ast32(dst + (ubase + q) * 8 + n16,     (((unsigned)f2bf(hv0)) << 16) | 1u);
      ast32(dst + (ubase + 4 + q) * 8 + n16, (((unsigned)f2bf(hv1)) << 16) | 1u);
    }

    // ---- issue next step's bulk h reads: flight overlaps store landing ----
    if (t + 1 < steps) {
      const unsigned* src = hio + (size_t)(t + 1) * 2560 + wave * 320 + lane;
#pragma unroll
      for (int j = 0; j < 5; j++) hv5[j] = ald32(src + j * 64);
    }
  }
}

// ---------------- per-cell logsumexp over V: produce lb[b][t][u], ly[b][t][u] ----------------
__global__ __launch_bounds__(256) void lse_kernel(
    const float* __restrict__ enc2, const float* __restrict__ dec2,
    const int* __restrict__ ys, float* __restrict__ lb, float* __restrict__ ly)
{
  const int blk = blockIdx.x;                // 4000 = 8*500
  const int b = blk / TT, t = blk - b * TT;
  const int wave = threadIdx.x >> 6, lane = threadIdx.x & 63;
  const float* er = enc2 + ((size_t)t * 16 + b) * VV;
  const float e0 = er[lane], e1 = er[lane + 64];
  for (int u = wave; u < UP1; u += 4) {
    const float* dr = dec2 + ((size_t)u * 16 + b) * VV;
    float s0 = e0 + dr[lane], s1 = e1 + dr[lane + 64];
    float mx = fmaxf(s0, s1);
#pragma unroll
    for (int off = 32; off >= 1; off >>= 1) mx = fmaxf(mx, __shfl_xor(mx, off));
    float p = __expf(s0 - mx) + __expf(s1 - mx);
#pragma unroll
    for (int off = 32; off >= 1; off >>= 1) p += __shfl_xor(p, off);
    float lsev = mx + __logf(p);
    if (u < UU) {
      int y = ys[b * UU + u];                // in [1,127]
      float sy = (y < 64) ? __shfl(s0, y) : __shfl(s1, y - 64);
      if (lane == 0) ly[((size_t)b * TT + t) * UU + u] = sy - lsev;
    }
    if (lane == 0) lb[((size_t)b * TT + t) * UP1 + u] = s0 - lsev;  // lane0: v=0
  }
}

// ---------------- anti-diagonal DP: single wave/sample, barrier-free, depth-4 prefetch ----------------
#define DP_ISSUE(D, LB0, LY0, LB1, LY1) {                                        \
  int t0_ = (D) - u0, t1_ = (D) - u1;                                            \
  LB0 = (u0 <= UU && t0_ >= 1 && t0_ < TT) ? lb[((size_t)b*TT + t0_-1)*UP1 + u0] : 0.f; \
  LY0 = (u0 >= 1 && u0 <= UU && t0_ >= 0 && t0_ < TT) ? ly[((size_t)b*TT + t0_)*UU + u0-1] : 0.f; \
  LB1 = (u1 <= UU && t1_ >= 1 && t1_ < TT) ? lb[((size_t)b*TT + t1_-1)*UP1 + u1] : 0.f; \
  LY1 = (u1 >= 1 && u1 <= UU && t1_ >= 0 && t1_ < TT) ? ly[((size_t)b*TT + t1_)*UU + u1-1] : 0.f; }

#define DP_PROC(D, LB0, LY0, LB1, LY1) {                                         \
  float am1 = __shfl_up(alpha1, 1);                                              \
  float old0 = alpha0, old1 = alpha1;                                            \
  int t0_ = (D) - u0;                                                            \
  if (u0 <= UU && t0_ >= 0 && t0_ < TT) {                                        \
    float a1 = (t0_ >= 1) ? old0 + LB0 : NEG;                                    \
    float a2 = (u0 >= 1) ? am1 + LY0 : NEG;                                      \
    float m = fmaxf(a1, a2);                                                     \
    float val = (m <= -1e29f) ? NEG : m + __logf(1.f + __expf(-fabsf(a1 - a2))); \
    alpha0 = val;                                                                \
    if (t0_ == tl - 1 && u0 == ul)                                               \
      atomicAdd(out, -0.125f * (val + lb[((size_t)b*TT + t0_)*UP1 + u0]));       \
  }                                                                              \
  int t1_ = (D) - u1;                                                            \
  if (u1 <= UU && t1_ >= 0 && t1_ < TT) {                                        \
    float a1 = (t1_ >= 1) ? old1 + LB1 : NEG;                                    \
    float a2 = old0 + LY1;                                                       \
    float m = fmaxf(a1, a2);                                                     \
    float val = (m <= -1e29f) ? NEG : m + __logf(1.f + __expf(-fabsf(a1 - a2))); \
    alpha1 = val;                                                                \
    if (t1_ == tl - 1 && u1 == ul)                                               \
      atomicAdd(out, -0.125f * (val + lb[((size_t)b*TT + t1_)*UP1 + u1]));       \
  } }

__global__ __launch_bounds__(64) void dp_kernel(
    const float* __restrict__ lb, const float* __restrict__ ly,
    const int* __restrict__ xlen, const int* __restrict__ ylen,
    float* __restrict__ out)
{
  const int b = blockIdx.x;
  const int l = threadIdx.x;
  const int u0 = 2 * l, u1 = 2 * l + 1;
  const int tl = xlen[b], ul = ylen[b];
  const float NEG = -1e30f;
  float alpha0 = (l == 0) ? 0.f : NEG;
  float alpha1 = NEG;

  float A0, A1, A2, A3, B0, B1, B2, B3, C0, C1, C2, C3, D0, D1, D2, D3;
  DP_ISSUE(1, A0, A1, A2, A3)
  DP_ISSUE(2, B0, B1, B2, B3)
  DP_ISSUE(3, C0, C1, C2, C3)
  DP_ISSUE(4, D0, D1, D2, D3)
  for (int d = 1; d <= TT - 1 + UU; d += 4) {            // 619 diagonals
    DP_PROC(d, A0, A1, A2, A3)
    if (d + 4 <= TT - 1 + UU) DP_ISSUE(d + 4, A0, A1, A2, A3)
    if (d + 1 <= TT - 1 + UU) {
      DP_PROC(d + 1, B0, B1, B2, B3)
      if (d + 5 <= TT - 1 + UU) DP_ISSUE(d + 5, B0, B1, B2, B3)
    }
    if (d + 2 <= TT - 1 + UU) {
      DP_PROC(d + 2, C0, C1, C2, C3)
      if (d + 6 <= TT - 1 + UU) DP_ISSUE(d + 6, C0, C1, C2, C3)
    }
    if (d + 3 <= TT - 1 + UU) {
      DP_PROC(d + 3, D0, D1, D2, D3)
      if (d + 7 <= TT - 1 + UU) DP_ISSUE(d + 7, D0, D1, D2, D3)
    }
  }
}

// ---------------- launch ----------------
extern "C" void kernel_launch(void* const* d_in, const int* in_sizes, int n_in,
                              void* d_out, int out_size, void* d_ws, size_t ws_size,
                              hipStream_t stream) {
  (void)in_sizes; (void)n_in; (void)out_size;
  const float* xs    = (const float*)d_in[0];
  const int*   ys    = (const int*)d_in[1];
  const int*   xlen  = (const int*)d_in[2];
  const int*   ylen  = (const int*)d_in[3];
  const float* eWih0 = (const float*)d_in[4];
  const float* eWhh0 = (const float*)d_in[5];
  const float* ebih0 = (const float*)d_in[6];
  const float* ebhh0 = (const float*)d_in[7];
  const float* eWih1 = (const float*)d_in[8];
  const float* eWhh1 = (const float*)d_in[9];
  const float* ebih1 = (const float*)d_in[10];
  const float* ebhh1 = (const float*)d_in[11];
  const float* eWo   = (const float*)d_in[12];
  const float* ebo   = (const float*)d_in[13];
  const float* dWih  = (const float*)d_in[15];
  const float* dWhh  = (const float*)d_in[16];
  const float* dbih  = (const float*)d_in[17];
  const float* dbhh  = (const float*)d_in[18];
  const float* dWo   = (const float*)d_in[19];
  const float* dbo   = (const float*)d_in[20];

  char* ws = (char*)d_ws;
  const size_t OFF_XP0   = 1024;
  const size_t OFF_XPD   = OFF_XP0   + 20480000;  // 8*500*1280 f32
  const size_t OFF_H0    = OFF_XPD   + 4956160;   // 501 * 2560 u32 (tagged, [u][b])
  const size_t OFF_H1    = OFF_H0    + 5130240;
  const size_t OFF_HD    = OFF_H1    + 5130240;   // 122 * 2560 u32
  const size_t OFF_WIH0B = OFF_HD    + 1249280;   // 1280*96 bf16
  const size_t OFF_XSB   = OFF_WIH0B + 245760;    // 4000*96 bf16
  const size_t OFF_B1P   = OFF_XSB   + 768000;
  const size_t OFF_B0S   = OFF_B1P   + 5120;
  const size_t OFF_ENC2  = OFF_B0S   + 5120;
  const size_t OFF_DEC2  = OFF_ENC2  + 4096000;   // 500*16*128 f32
  const size_t OFF_LB    = OFF_DEC2  + 991232;    // 121*16*128 f32
  const size_t OFF_LY    = OFF_LB    + 1936000;   // 8*500*121 f32
  const size_t OFF_XP1   = OFF_LY    + 1920000;   // 500*8*1280 tagged f32
  const size_t TOTAL     = OFF_XP1   + 20480000;
  if (ws_size < TOTAL) return;

  float*    xp0   = (float*)(ws + OFF_XP0);
  float*    xpd   = (float*)(ws + OFF_XPD);
  unsigned* h0    = (unsigned*)(ws + OFF_H0);
  unsigned* h1    = (unsigned*)(ws + OFF_H1);
  unsigned* hd    = (unsigned*)(ws + OFF_HD);
  ushort*   wih0b = (ushort*)(ws + OFF_WIH0B);
  ushort*   xsb   = (ushort*)(ws + OFF_XSB);
  float*    b1p   = (float*)(ws + OFF_B1P);
  float*    b0s   = (float*)(ws + OFF_B0S);
  float*    enc2  = (float*)(ws + OFF_ENC2);
  float*    dec2  = (float*)(ws + OFF_DEC2);
  float*    lb    = (float*)(ws + OFF_LB);
  float*    ly    = (float*)(ws + OFF_LY);
  unsigned* xp1   = (unsigned*)(ws + OFF_XP1);
  float*    out   = (float*)d_out;

  hipLaunchKernelGGL(prep_w, dim3(2958), dim3(256), 0, stream,
                     eWih0, xs, ebih1, ebhh1, ebih0, ebhh0,
                     ys, dWih, dbih, dbhh,
                     wih0b, xsb, b1p, b0s, xpd, out);
  hipLaunchKernelGGL(xproj0_mfma, dim3(250), dim3(256), 0, stream, xsb, wih0b, b0s, xp0);
  hipLaunchKernelGGL(lstm_fused, dim3(24), dim3(512), 0, stream,
                     eWhh0, eWih1, eWhh1, dWhh, b1p, xp0, xpd, h0, h1, hd, xp1,
                     eWo, dWo, ebo, dbo, enc2, dec2);
  hipLaunchKernelGGL(lse_kernel, dim3(4000), dim3(256), 0, stream, enc2, dec2, ys, lb, ly);
  hipLaunchKernelGGL(dp_kernel, dim3(8), dim3(64), 0, stream, lb, ly, xlen, ylen, out);
}

// Round 13
// 1672.558 us; speedup vs baseline: 3.6876x; 1.2336x over previous
//
#include <hip/hip_runtime.h>

typedef __attribute__((ext_vector_type(8))) short s8v;   // 8 x bf16 (4 VGPRs)
typedef __attribute__((ext_vector_type(4))) float f4v;   // MFMA accumulator

#define BB 8
#define TT 500
#define UU 120
#define UP1 121
#define VV 128
#define HH 320
#define G4 1280

// ---------------- helpers ----------------
__device__ __forceinline__ unsigned short f2bf(float x) {
  unsigned u = __builtin_bit_cast(unsigned, x);
  unsigned r = (u + 0x7FFFu + ((u >> 16) & 1u)) >> 16;  // RNE
  return (unsigned short)r;
}
__device__ __forceinline__ s8v ld8bf(const float* p) {  // 8 f32 -> s8v bf16
  s8v r;
#pragma unroll
  for (int j = 0; j < 8; j++) r[j] = (short)f2bf(p[j]);
  return r;
}
__device__ __forceinline__ float sigf(float x)   { return 1.f / (1.f + __expf(-x)); }
__device__ __forceinline__ float tanh_f(float x) { return 2.f / (1.f + __expf(-2.f * x)) - 1.f; }

// agent-scope (L3-coherent) relaxed atomics — proven transport
__device__ __forceinline__ unsigned ald32(const unsigned* p) {
  return __hip_atomic_load((unsigned*)p, __ATOMIC_RELAXED, __HIP_MEMORY_SCOPE_AGENT);
}
__device__ __forceinline__ void ast32(unsigned* p, unsigned v) {
  __hip_atomic_store(p, v, __ATOMIC_RELAXED, __HIP_MEMORY_SCOPE_AGENT);
}

// ---------------- prep: conversions + bias folds + xprojd + out-zero ----------------
__global__ __launch_bounds__(256) void prep_w(
    const float* __restrict__ wih0, const float* __restrict__ xs,
    const float* __restrict__ bih1, const float* __restrict__ bhh1,
    const float* __restrict__ bih0, const float* __restrict__ bhh0,
    const int* __restrict__ ys, const float* __restrict__ dWih,
    const float* __restrict__ dbih, const float* __restrict__ dbhh,
    ushort* __restrict__ wih0b, ushort* __restrict__ xsb,
    float* __restrict__ bias1p, float* __restrict__ b0s,
    float* __restrict__ xpd, float* __restrict__ out)
{
  if (blockIdx.x >= 1990) {                  // ---- xprojd section ----
    const int blk = blockIdx.x - 1990;       // 968 = 8 * 121
    const int b = blk / UP1, u = blk - b * UP1;
    int colv = -1;
    if (u > 0) colv = ys[b * UU + (u - 1)] - 1;
    for (int i = threadIdx.x; i < G4; i += 256) {
      int uu = i >> 2, gg = i & 3;
      int row = gg * HH + uu;
      float v = dbih[row] + dbhh[row];
      if (colv >= 0) v += dWih[row * 127 + colv];
      xpd[((size_t)b * UP1 + u) * G4 + i] = v;
    }
    return;
  }
  int i = blockIdx.x * blockDim.x + threadIdx.x;
  if (i == 0) out[0] = 0.f;
  if (i < 122880) {                          // Wih0 [1280][80] -> [1280][96] padded
    int row = i / 96, k = i - row * 96;
    wih0b[i] = (k < 80) ? f2bf(wih0[row * 80 + k]) : (ushort)0;
  } else if (i < 506880) {                   // xs [4000][80] -> [4000][96] padded
    int e = i - 122880;
    int row = e / 96, k = e - row * 96;
    xsb[e] = (k < 80) ? f2bf(xs[row * 80 + k]) : (ushort)0;
  } else if (i < 508160) {                   // bias1 permuted [unit][gate]
    int e = i - 506880;
    int uq = e >> 2, gq = e & 3;
    bias1p[e] = bih1[gq * HH + uq] + bhh1[gq * HH + uq];
  } else if (i < 509440) {                   // bih0+bhh0 summed (gate-row order)
    int e = i - 508160;
    b0s[e] = bih0[e] + bhh0[e];
  }
}

// ---------------- xproj for layer0: [4000,96]bf16 @ [96,1280] -> xp0[b][t][u][g] f32 ----------------
__global__ __launch_bounds__(256) void xproj0_mfma(
    const ushort* __restrict__ xsb, const ushort* __restrict__ wih0b,
    const float* __restrict__ b0s, float* __restrict__ xp0)
{
  const int mt = blockIdx.x;                 // 250 tiles of 16 (b,t)-rows
  const int wave = threadIdx.x >> 6, lane = threadIdx.x & 63;
  const int q = lane >> 4, n16 = lane & 15;
  s8v a[3];
#pragma unroll
  for (int kt = 0; kt < 3; kt++)
    a[kt] = *(const s8v*)(xsb + (mt * 16 + n16) * 96 + kt * 32 + q * 8);
  for (int nt = wave; nt < 80; nt += 4) {
    s8v bf[3];
#pragma unroll
    for (int kt = 0; kt < 3; kt++)
      bf[kt] = *(const s8v*)(wih0b + (nt * 16 + n16) * 96 + kt * 32 + q * 8);
    f4v acc = {0.f, 0.f, 0.f, 0.f};
#pragma unroll
    for (int kt = 0; kt < 3; kt++)
      acc = __builtin_amdgcn_mfma_f32_16x16x32_bf16(a[kt], bf[kt], acc, 0, 0, 0);
    const int gr = nt * 16 + n16;            // D col = gate row
    const int gg = gr / HH;
    const int uu = gr - gg * HH;
    const float bias = b0s[gr];
#pragma unroll
    for (int r = 0; r < 4; r++) {
      int bt = mt * 16 + 4 * q + r;          // D row = (b,t) row
      xp0[(size_t)bt * G4 + uu * 4 + gg] = acc[r] + bias;
    }
  }
}

// ======================================================================
// Fused pipeline v10: ONE 256-block grid, 1 block/CU (103KB LDS), all
// co-resident BY CAPACITY (no dispatch-order assumption):
//   wg 0-4  : stage0, wg 5-9: stage1, wg 10-14: dec   (R8-proven)
//   wg 15-19: relay xp1 = Wih1@h0[s+1] + b1
//   wg 20-22: enc proj (t stride 3) -> TAGGED enc2; wg 23: dec proj -> dec2
//   wg 24-247: 224 LSE workers — cells c = w, w+224, ... (t-major, so each
//     worker's next cell arrives ~84us after its last). Poll enc2/dec2 row
//     tags with s_sleep(16) (matches ~3us/t production rate; traffic ~16x
//     below the R0 poll-storm level), compute lb/ly TAGGED.
//   wg 248-255: dp, one sample each — R10's proven tagged-dp form.
// R10's fused-lse failure was giving LSE only 4 WGs; 224 blocks is more
// parallelism than the standalone 4000-block kernel averaged. LSE rides the
// idle 232 CUs inside the lstm window; dp trails the last cell by ~50us.
// ======================================================================
__global__ __launch_bounds__(512, 1) void lstm_fused(
    const float* __restrict__ eWhh0, const float* __restrict__ eWih1,
    const float* __restrict__ eWhh1, const float* __restrict__ dWhh,
    const float* __restrict__ b1p,
    const float* __restrict__ xp0, const float* __restrict__ xpd,
    unsigned* __restrict__ h0u, unsigned* __restrict__ h1u, unsigned* __restrict__ hdu,
    unsigned* __restrict__ xp1u,
    const float* __restrict__ eWo, const float* __restrict__ dWo,
    const float* __restrict__ ebo, const float* __restrict__ dbo,
    float* __restrict__ enc2, float* __restrict__ dec2,
    float* __restrict__ lbp, float* __restrict__ lyp,
    const int* __restrict__ ys, const int* __restrict__ xlen,
    const int* __restrict__ ylen, float* __restrict__ out)
{
  __shared__ ushort hbS[2][16][328];         // 21KB  h double-buffer [b][u]
  __shared__ s8v wlds[8][10][64];            // 80KB  tile1 weight frags / proj Wo

  const int wg = blockIdx.x;
  const int tid = threadIdx.x;
  const int wave = tid >> 6, lane = tid & 63;
  const int q = lane >> 4, n16 = lane & 15;
  const int uloc = n16 >> 2, g = n16 & 3;
  const int bcol = n16 & 7;
  const bool act = (n16 < BB);

  if (wg >= 248) {
    // ================= dp: RNN-T forward DP, one sample per block =================
    if (tid >= 64) return;
    const int b = wg - 248;
    const int l = tid;
    const int u0 = 2 * l, u1 = 2 * l + 1;
    const int tl = xlen[b], ul = ylen[b];
    const float NEG = -1e30f;
    const unsigned* lbu = (const unsigned*)lbp;
    const unsigned* lyu = (const unsigned*)lyp;
    float alpha0 = (l == 0) ? 0.f : NEG;
    float alpha1 = NEG;

    int pt0 = 1 - u0, pt1 = 1 - u1;
    bool vb0 = (u0 <= UU && pt0 >= 1 && pt0 < TT);
    bool vy0 = (u0 >= 1 && u0 <= UU && pt0 >= 0 && pt0 < TT);
    bool vb1 = (u1 <= UU && pt1 >= 1 && pt1 < TT);
    bool vy1 = (u1 >= 1 && u1 <= UU && pt1 >= 0 && pt1 < TT);
    unsigned nb0 = vb0 ? ald32(lbu + ((size_t)b * TT + pt0 - 1) * UP1 + u0) : 1u;
    unsigned ny0 = vy0 ? ald32(lyu + ((size_t)b * TT + pt0) * UU + (u0 - 1)) : 1u;
    unsigned nb1 = vb1 ? ald32(lbu + ((size_t)b * TT + pt1 - 1) * UP1 + u1) : 1u;
    unsigned ny1 = vy1 ? ald32(lyu + ((size_t)b * TT + pt1) * UU + (u1 - 1)) : 1u;

    for (int d = 1; d <= TT - 1 + UU; d++) {
      {
        int tries = 0;
        for (;;) {
          unsigned m = nb0 & ny0 & nb1 & ny1;
          if (__all((int)(m & 1u)) || ++tries > (1 << 15)) break;
          if (tries > 8) __builtin_amdgcn_s_sleep(8);
          int t0 = d - u0, t1 = d - u1;
          if (vb0) nb0 = ald32(lbu + ((size_t)b * TT + t0 - 1) * UP1 + u0);
          if (vy0) ny0 = ald32(lyu + ((size_t)b * TT + t0) * UU + (u0 - 1));
          if (vb1) nb1 = ald32(lbu + ((size_t)b * TT + t1 - 1) * UP1 + u1);
          if (vy1) ny1 = ald32(lyu + ((size_t)b * TT + t1) * UU + (u1 - 1));
        }
      }
      float lb0 = vb0 ? __uint_as_float(nb0 & ~1u) : 0.f;
      float ly0 = vy0 ? __uint_as_float(ny0 & ~1u) : 0.f;
      float lb1 = vb1 ? __uint_as_float(nb1 & ~1u) : 0.f;
      float ly1 = vy1 ? __uint_as_float(ny1 & ~1u) : 0.f;
      pt0 = (d + 1) - u0; pt1 = (d + 1) - u1;
      vb0 = (u0 <= UU && pt0 >= 1 && pt0 < TT);
      vy0 = (u0 >= 1 && u0 <= UU && pt0 >= 0 && pt0 < TT);
      vb1 = (u1 <= UU && pt1 >= 1 && pt1 < TT);
      vy1 = (u1 >= 1 && u1 <= UU && pt1 >= 0 && pt1 < TT);
      nb0 = vb0 ? ald32(lbu + ((size_t)b * TT + pt0 - 1) * UP1 + u0) : 1u;
      ny0 = vy0 ? ald32(lyu + ((size_t)b * TT + pt0) * UU + (u0 - 1)) : 1u;
      nb1 = vb1 ? ald32(lbu + ((size_t)b * TT + pt1 - 1) * UP1 + u1) : 1u;
      ny1 = vy1 ? ald32(lyu + ((size_t)b * TT + pt1) * UU + (u1 - 1)) : 1u;

      float am1 = __shfl_up(alpha1, 1);
      float old0 = alpha0, old1 = alpha1;
      int t0 = d - u0;
      if (u0 <= UU && t0 >= 0 && t0 < TT) {
        float a1 = (t0 >= 1) ? old0 + lb0 : NEG;
        float a2 = (u0 >= 1) ? am1 + ly0 : NEG;
        float m = fmaxf(a1, a2);
        float val = (m <= -1e29f) ? NEG : m + __logf(1.f + __expf(-fabsf(a1 - a2)));
        alpha0 = val;
        if (t0 == tl - 1 && u0 == ul) {
          unsigned lt; int tr = 0;
          for (;;) { lt = ald32(lbu + ((size_t)b * TT + t0) * UP1 + u0);
                     if ((lt & 1u) || ++tr > (1 << 15)) break;
                     __builtin_amdgcn_s_sleep(8); }
          atomicAdd(out, -0.125f * (val + __uint_as_float(lt & ~1u)));
        }
      }
      int t1 = d - u1;
      if (u1 <= UU && t1 >= 0 && t1 < TT) {
        float a1 = (t1 >= 1) ? old1 + lb1 : NEG;
        float a2 = old0 + ly1;                 // u1 odd => u1>=1 always
        float m = fmaxf(a1, a2);
        float val = (m <= -1e29f) ? NEG : m + __logf(1.f + __expf(-fabsf(a1 - a2)));
        alpha1 = val;
        if (t1 == tl - 1 && u1 == ul) {
          unsigned lt; int tr = 0;
          for (;;) { lt = ald32(lbu + ((size_t)b * TT + t1) * UP1 + u1);
                     if ((lt & 1u) || ++tr > (1 << 15)) break;
                     __builtin_amdgcn_s_sleep(8); }
          atomicAdd(out, -0.125f * (val + __uint_as_float(lt & ~1u)));
        }
      }
    }
    return;
  }

  if (wg >= 24) {
    // ================= LSE workers: cells c = w, w+224, ... (t-major) =================
    const int w0 = wg - 24;
    const unsigned* e2u = (const unsigned*)enc2;
    const unsigned* d2u = (const unsigned*)dec2;
    for (int c = w0; c < 4000; c += 224) {
      const int t = c >> 3, b = c & 7;
      // poll enc2[t,b] row tags (each wave loads the full 128-wide row)
      const unsigned* er = e2u + ((size_t)t * 16 + b) * VV;
      unsigned ev0, ev1;
      {
        int tries = 0;
        for (;;) {
          ev0 = ald32(er + lane); ev1 = ald32(er + lane + 64);
          if (__all((int)(ev0 & ev1 & 1u)) || ++tries > (1 << 14)) break;
          if (tries > 2) __builtin_amdgcn_s_sleep(16);
        }
      }
      const float e0 = __uint_as_float(ev0 & ~1u);
      const float e1 = __uint_as_float(ev1 & ~1u);
      for (int u = wave; u < UP1; u += 8) {
        const unsigned* dr = d2u + ((size_t)u * 16 + b) * VV;
        unsigned dv0, dv1;
        int tr2 = 0;
        for (;;) {
          dv0 = ald32(dr + lane); dv1 = ald32(dr + lane + 64);
          if (__all((int)(dv0 & dv1 & 1u)) || ++tr2 > (1 << 14)) break;
          if (tr2 > 2) __builtin_amdgcn_s_sleep(16);
        }
        float s0 = e0 + __uint_as_float(dv0 & ~1u);
        float s1 = e1 + __uint_as_float(dv1 & ~1u);
        float mx = fmaxf(s0, s1);
#pragma unroll
        for (int off = 32; off >= 1; off >>= 1) mx = fmaxf(mx, __shfl_xor(mx, off));
        float p = __expf(s0 - mx) + __expf(s1 - mx);
#pragma unroll
        for (int off = 32; off >= 1; off >>= 1) p += __shfl_xor(p, off);
        float lsev = mx + __logf(p);
        if (u < UU) {
          int y = ys[b * UU + u];              // in [1,127]
          float sy = (y < 64) ? __shfl(s0, y) : __shfl(s1, y - 64);
          if (lane == 0)
            ast32((unsigned*)(lyp + ((size_t)b * TT + t) * UU + u),
                  __float_as_uint(sy - lsev) | 1u);
        }
        if (lane == 0)
          ast32((unsigned*)(lbp + ((size_t)b * TT + t) * UP1 + u),
                __float_as_uint(s0 - lsev) | 1u);
      }
    }
    return;
  }

  // zero both LDS h buffers (pipeline branches only)
  for (int i = tid; i < 2 * 16 * 328; i += 512) ((ushort*)hbS)[i] = 0;

  if (wg >= 20) {
    // ================= streaming output projections (TAGGED outputs) =================
    const bool isenc = (wg < 23);
    const unsigned* hsrc = isenc ? h1u : hdu;
    const float* wsrc = isenc ? eWo : dWo;   // f32, converted on stage-in
    const float* bsrc = isenc ? ebo : dbo;
    float* osrc = isenc ? enc2 : dec2;
    const int tstart = isenc ? (wg - 20) : 0;
    const int tstep = isenc ? 3 : 1;
    const int tmax = isenc ? TT : UP1;
    ushort* wl = (ushort*)wlds;
    for (int i = tid; i < 40960; i += 512) wl[i] = f2bf(wsrc[i]);
    __syncthreads();
    const int nt = wave;                     // 8 col-tiles of 16
    const int vc = nt * 16 + n16;
    const float bias = bsrc[vc];
    s8v bf[10];
#pragma unroll
    for (int kt = 0; kt < 10; kt++)
      bf[kt] = *(const s8v*)(wl + (size_t)vc * HH + kt * 32 + q * 8);

    for (int t = tstart; t < tmax; t += tstep) {
      const unsigned* src = hsrc + (size_t)(t + 1) * 2560 + wave * 320 + lane;
      unsigned v[5];
#pragma unroll
      for (int j = 0; j < 5; j++) v[j] = ald32(src + j * 64);
      int tries = 0;
      for (;;) {
        unsigned a = v[0] & v[1] & v[2] & v[3] & v[4];
        if (__all((int)(a & 1u)) || ++tries > (1 << 17)) break;
        if (tries > 64) __builtin_amdgcn_s_sleep(1);
#pragma unroll
        for (int j = 0; j < 5; j++) v[j] = ald32(src + j * 64);
      }
#pragma unroll
      for (int j = 0; j < 5; j++) {
        int f = wave * 320 + j * 64 + lane;            // u = f>>3, b = f&7
        hbS[0][f & 7][f >> 3] = (ushort)(v[j] >> 16);
      }
      __syncthreads();
      s8v a[10];
#pragma unroll
      for (int kt = 0; kt < 10; kt++)
        a[kt] = *(const s8v*)&hbS[0][n16][kt * 32 + q * 8];
      f4v acc = {0.f, 0.f, 0.f, 0.f};
#pragma unroll
      for (int kt = 0; kt < 10; kt++)
        acc = __builtin_amdgcn_mfma_f32_16x16x32_bf16(a[kt], bf[kt], acc, 0, 0, 0);
      if (q < 2) {
#pragma unroll
        for (int r = 0; r < 4; r++) {
          int b = 4 * q + r;                 // D row = batch
          ast32((unsigned*)&osrc[((size_t)t * 16 + b) * VV + vc],
                __float_as_uint(acc[r] + bias) | 1u);
        }
      }
      __syncthreads();                       // before next t overwrites hbS
    }
    return;
  }

  if (wg >= 15) {
    // ================= relay: xp1[s] = Wih1 @ h0[s+1] + b1 =================
    const int rw = wg - 15;
    const int w = rw * 8 + wave;
    const int ubase = w * 8;
    s8v afr0[10];
    {
      const int arow0 = g * HH + ubase + uloc;
      const int arow1 = g * HH + ubase + 4 + uloc;
#pragma unroll
      for (int kt = 0; kt < 10; kt++) {
        afr0[kt] = ld8bf(eWih1 + (size_t)arow0 * HH + kt * 32 + q * 8);
        wlds[wave][kt][lane] = ld8bf(eWih1 + (size_t)arow1 * HH + kt * 32 + q * 8);
      }
    }
    f4v bias4[2];
#pragma unroll
    for (int tile = 0; tile < 2; tile++)
      bias4[tile] = *(const f4v*)(b1p + (ubase + tile * 4 + q) * 4);

    unsigned v[5];
    {
      const unsigned* p = h0u + 2560 + wave * 320 + lane;
#pragma unroll
      for (int j = 0; j < 5; j++) v[j] = ald32(p + j * 64);
    }
    __syncthreads();                         // weight-LDS + hbS zeros visible

    for (int s = 0; s < TT; s++) {
      const int pb = s & 1;
      {
        const unsigned* p = h0u + (size_t)(s + 1) * 2560 + wave * 320 + lane;
        int tries = 0;
        for (;;) {
          unsigned a = v[0] & v[1] & v[2] & v[3] & v[4];
          if (__all((int)(a & 1u)) || ++tries > (1 << 17)) break;
          if (tries > 64) __builtin_amdgcn_s_sleep(1);
#pragma unroll
          for (int j = 0; j < 5; j++) v[j] = ald32(p + j * 64);
        }
#pragma unroll
        for (int j = 0; j < 5; j++) {
          int f = wave * 320 + j * 64 + lane;          // u = f>>3, b = f&7
          hbS[pb][f & 7][f >> 3] = (ushort)(v[j] >> 16);
        }
      }
      __syncthreads();
      if (s + 1 < TT) {
        const unsigned* p = h0u + (size_t)(s + 2) * 2560 + wave * 320 + lane;
#pragma unroll
        for (int j = 0; j < 5; j++) v[j] = ald32(p + j * 64);
      }

      f4v acc[2];
      acc[0] = bias4[0]; acc[1] = bias4[1];
#pragma unroll
      for (int kt = 0; kt < 10; kt++) {
        s8v b = *(const s8v*)&hbS[pb][n16][kt * 32 + q * 8];
        acc[0] = __builtin_amdgcn_mfma_f32_16x16x32_bf16(afr0[kt], b, acc[0], 0, 0, 0);
        s8v a1 = wlds[wave][kt][lane];
        acc[1] = __builtin_amdgcn_mfma_f32_16x16x32_bf16(a1, b, acc[1], 0, 0, 0);
      }
      if (act) {
#pragma unroll
        for (int tile = 0; tile < 2; tile++) {
          unsigned* dp = xp1u + (size_t)((unsigned)s * 8u + (unsigned)n16) * G4
                       + (unsigned)((ubase + tile * 4 + q) * 4);
#pragma unroll
          for (int r = 0; r < 4; r++)
            ast32(dp + r, __float_as_uint(acc[tile][r]) | 1u);   // LSB tag on f32
        }
      }
    }
    return;
  }

  // ================= recurrent stages =================
  const int stage = wg / 5;
  const int gw = wg - stage * 5;
  const int w = gw * 8 + wave;              // wave-in-stage [0,40)
  const int ubase = w * 8;                  // this wave owns units [ubase, ubase+8)

  const float* Af = (stage == 0) ? eWhh0 : ((stage == 1) ? eWhh1 : dWhh);
  // tile0 -> regs (40 VGPR), tile1 -> LDS; converted inline from f32
  s8v afr0[10];
  {
    const int arow0 = g * HH + ubase + uloc;
    const int arow1 = g * HH + ubase + 4 + uloc;
#pragma unroll
    for (int kt = 0; kt < 10; kt++) {
      afr0[kt] = ld8bf(Af + (size_t)arow0 * HH + kt * 32 + q * 8);
      wlds[wave][kt][lane] = ld8bf(Af + (size_t)arow1 * HH + kt * 32 + q * 8);
    }
  }

  const int steps = (stage == 2) ? UP1 : TT;
  unsigned* hio = (stage == 0) ? h0u : ((stage == 1) ? h1u : hdu);

  const float* xq = 0;
  if (stage == 0)      xq = xp0 + (size_t)bcol * TT * G4;
  else if (stage == 2) xq = xpd + (size_t)bcol * UP1 * G4;

  float c0 = 0.f, c1 = 0.f;
  unsigned hv5[5];                           // in-flight bulk h reads
  __syncthreads();                           // LDS zeros + weight-LDS visible

  for (int t = 0; t < steps; t++) {
    const int pb = t & 1;

    // ---- pre-issue C-init inputs; consumed after the MFMA block ----
    f4v xq4[2];
    unsigned xv[2][4];
    if (stage != 1) {
#pragma unroll
      for (int tile = 0; tile < 2; tile++)
        xq4[tile] = *(const f4v*)(xq + (size_t)t * G4 + (ubase + tile * 4 + q) * 4);
    } else {
#pragma unroll
      for (int tile = 0; tile < 2; tile++) {
        const unsigned* xpp = xp1u + (size_t)((unsigned)t * 8u + (unsigned)bcol) * G4
                            + (unsigned)((ubase + tile * 4 + q) * 4);
#pragma unroll
        for (int r = 0; r < 4; r++) xv[tile][r] = ald32(xpp + r);
      }
    }

    // ---- resolve pre-issued bulk h[t] reads, transpose-relay into LDS ----
    if (t > 0) {
      const unsigned* src = hio + (size_t)t * 2560 + wave * 320 + lane;
      int tries = 0;
      for (;;) {
        unsigned a = hv5[0] & hv5[1] & hv5[2] & hv5[3] & hv5[4];
        if (__all((int)(a & 1u)) || ++tries > (1 << 17)) break;
        if (tries > 64) __builtin_amdgcn_s_sleep(1);
#pragma unroll
        for (int j = 0; j < 5; j++) hv5[j] = ald32(src + j * 64);
      }
#pragma unroll
      for (int j = 0; j < 5; j++) {
        int f = wave * 320 + j * 64 + lane;            // u = f>>3, b = f&7
        hbS[pb][f & 7][f >> 3] = (ushort)(hv5[j] >> 16);
      }
    }
    __syncthreads();

    // ---- MFMAs: B-frags from LDS h(t); tile1 A-frags from LDS ----
    f4v acc[2];
    acc[0] = (f4v){0.f, 0.f, 0.f, 0.f};
    acc[1] = (f4v){0.f, 0.f, 0.f, 0.f};
#pragma unroll
    for (int kt = 0; kt < 10; kt++) {
      s8v b = *(const s8v*)&hbS[pb][n16][kt * 32 + q * 8];
      acc[0] = __builtin_amdgcn_mfma_f32_16x16x32_bf16(afr0[kt], b, acc[0], 0, 0, 0);
      s8v a1 = wlds[wave][kt][lane];
      acc[1] = __builtin_amdgcn_mfma_f32_16x16x32_bf16(a1, b, acc[1], 0, 0, 0);
    }

    // ---- resolve C-init (deferred add; stage1 tag-spins on relay output) ----
    if (stage != 1) {
#pragma unroll
      for (int tile = 0; tile < 2; tile++) {
        acc[tile][0] += xq4[tile][0]; acc[tile][1] += xq4[tile][1];
        acc[tile][2] += xq4[tile][2]; acc[tile][3] += xq4[tile][3];
      }
    } else {
      int tries = 0;
      for (;;) {
        unsigned m = xv[0][0] & xv[0][1] & xv[0][2] & xv[0][3]
                   & xv[1][0] & xv[1][1] & xv[1][2] & xv[1][3];
        bool ok = (!act) || ((m & 1u) != 0u);
        if (__all((int)ok) || ++tries > (1 << 17)) break;
        if (tries > 64) __builtin_amdgcn_s_sleep(1);
#pragma unroll
        for (int tile = 0; tile < 2; tile++) {
          const unsigned* xpp = xp1u + (size_t)((unsigned)t * 8u + (unsigned)bcol) * G4
                              + (unsigned)((ubase + tile * 4 + q) * 4);
#pragma unroll
          for (int r = 0; r < 4; r++) xv[tile][r] = ald32(xpp + r);
        }
      }
#pragma unroll
      for (int tile = 0; tile < 2; tile++)
#pragma unroll
        for (int r = 0; r < 4; r++)
          acc[tile][r] += __uint_as_float(xv[tile][r] & ~1u);
    }

    // ---- lane-local LSTM cell ----
    float hv0, hv1;
    {
      float ig = sigf(acc[0][0]), fg = sigf(acc[0][1]);
      float gv = tanh_f(acc[0][2]), og = sigf(acc[0][3]);
      c0 = fg * c0 + ig * gv; hv0 = og * tanh_f(c0);
    }
    {
      float ig = sigf(acc[1][0]), fg = sigf(acc[1][1]);
      float gv = tanh_f(acc[1][2]), og = sigf(acc[1][3]);
      c1 = fg * c1 + ig * gv; hv1 = og * tanh_f(c1);
    }
    if (act) {
      // packed [u][b] store: wave's 16 stores span 2-4 cache lines; no drain
      unsigned* dst = hio + (size_t)(t + 1) * 2560;
      ast32(dst + (ubase + q) * 8 + n16,     (((unsigned)f2bf(hv0)) << 16) | 1u);
      ast32(dst + (ubase + 4 + q) * 8 + n16, (((unsigned)f2bf(hv1)) << 16) | 1u);
    }

    // ---- issue next step's bulk h reads: flight overlaps store landing ----
    if (t + 1 < steps) {
      const unsigned* src = hio + (size_t)(t + 1) * 2560 + wave * 320 + lane;
#pragma unroll
      for (int j = 0; j < 5; j++) hv5[j] = ald32(src + j * 64);
    }
  }
}

// ---------------- launch ----------------
extern "C" void kernel_launch(void* const* d_in, const int* in_sizes, int n_in,
                              void* d_out, int out_size, void* d_ws, size_t ws_size,
                              hipStream_t stream) {
  (void)in_sizes; (void)n_in; (void)out_size;
  const float* xs    = (const float*)d_in[0];
  const int*   ys    = (const int*)d_in[1];
  const int*   xlen  = (const int*)d_in[2];
  const int*   ylen  = (const int*)d_in[3];
  const float* eWih0 = (const float*)d_in[4];
  const float* eWhh0 = (const float*)d_in[5];
  const float* ebih0 = (const float*)d_in[6];
  const float* ebhh0 = (const float*)d_in[7];
  const float* eWih1 = (const float*)d_in[8];
  const float* eWhh1 = (const float*)d_in[9];
  const float* ebih1 = (const float*)d_in[10];
  const float* ebhh1 = (const float*)d_in[11];
  const float* eWo   = (const float*)d_in[12];
  const float* ebo   = (const float*)d_in[13];
  const float* dWih  = (const float*)d_in[15];
  const float* dWhh  = (const float*)d_in[16];
  const float* dbih  = (const float*)d_in[17];
  const float* dbhh  = (const float*)d_in[18];
  const float* dWo   = (const float*)d_in[19];
  const float* dbo   = (const float*)d_in[20];

  char* ws = (char*)d_ws;
  const size_t OFF_XP0   = 1024;
  const size_t OFF_XPD   = OFF_XP0   + 20480000;  // 8*500*1280 f32
  const size_t OFF_H0    = OFF_XPD   + 4956160;   // 501 * 2560 u32 (tagged, [u][b])
  const size_t OFF_H1    = OFF_H0    + 5130240;
  const size_t OFF_HD    = OFF_H1    + 5130240;   // 122 * 2560 u32
  const size_t OFF_WIH0B = OFF_HD    + 1249280;   // 1280*96 bf16
  const size_t OFF_XSB   = OFF_WIH0B + 245760;    // 4000*96 bf16
  const size_t OFF_B1P   = OFF_XSB   + 768000;
  const size_t OFF_B0S   = OFF_B1P   + 5120;
  const size_t OFF_ENC2  = OFF_B0S   + 5120;
  const size_t OFF_DEC2  = OFF_ENC2  + 4096000;   // 500*16*128 tagged f32
  const size_t OFF_LB    = OFF_DEC2  + 991232;    // 121*16*128 tagged f32
  const size_t OFF_LY    = OFF_LB    + 1936000;   // 8*500*121 tagged f32
  const size_t OFF_XP1   = OFF_LY    + 1920000;   // 500*8*1280 tagged f32
  const size_t TOTAL     = OFF_XP1   + 20480000;
  if (ws_size < TOTAL) return;

  float*    xp0   = (float*)(ws + OFF_XP0);
  float*    xpd   = (float*)(ws + OFF_XPD);
  unsigned* h0    = (unsigned*)(ws + OFF_H0);
  unsigned* h1    = (unsigned*)(ws + OFF_H1);
  unsigned* hd    = (unsigned*)(ws + OFF_HD);
  ushort*   wih0b = (ushort*)(ws + OFF_WIH0B);
  ushort*   xsb   = (ushort*)(ws + OFF_XSB);
  float*    b1p   = (float*)(ws + OFF_B1P);
  float*    b0s   = (float*)(ws + OFF_B0S);
  float*    enc2  = (float*)(ws + OFF_ENC2);
  float*    dec2  = (float*)(ws + OFF_DEC2);
  float*    lb    = (float*)(ws + OFF_LB);
  float*    ly    = (float*)(ws + OFF_LY);
  unsigned* xp1   = (unsigned*)(ws + OFF_XP1);
  float*    out   = (float*)d_out;

  hipLaunchKernelGGL(prep_w, dim3(2958), dim3(256), 0, stream,
                     eWih0, xs, ebih1, ebhh1, ebih0, ebhh0,
                     ys, dWih, dbih, dbhh,
                     wih0b, xsb, b1p, b0s, xpd, out);
  hipLaunchKernelGGL(xproj0_mfma, dim3(250), dim3(256), 0, stream, xsb, wih0b, b0s, xp0);
  hipLaunchKernelGGL(lstm_fused, dim3(256), dim3(512), 0, stream,
                     eWhh0, eWih1, eWhh1, dWhh, b1p, xp0, xpd, h0, h1, hd, xp1,
                     eWo, dWo, ebo, dbo, enc2, dec2, lb, ly,
                     ys, xlen, ylen, out);
}